// Round 1
// 268.396 us; speedup vs baseline: 1.0406x; 1.0406x over previous
//
#include <hip/hip_runtime.h>
#include <hip/hip_bf16.h>
#include <cmath>

#define Tt 2048
#define Cc 1024
#define Hh 16
#define HDd 64

typedef __attribute__((ext_vector_type(8))) short short8;
typedef __attribute__((ext_vector_type(4))) float f32x4;

// async global->LDS, 16B per lane; lds base must be wave-uniform
#define ASYNC16(gp, lp)                                       \
    __builtin_amdgcn_global_load_lds(                         \
        (const __attribute__((address_space(1))) void*)(gp),  \
        (__attribute__((address_space(3))) void*)(lp), 16, 0, 0)

__device__ __forceinline__ unsigned short f32_bf16(float f) {
    unsigned u = __float_as_uint(f);
    u += 0x7FFF + ((u >> 16) & 1);
    return (unsigned short)(u >> 16);
}
// 2-op round-to-nearest (ties away) — fine for finite values
__device__ __forceinline__ unsigned short f32_bf16_rn(float f) {
    return (unsigned short)((__float_as_uint(f) + 0x8000u) >> 16);
}
__device__ __forceinline__ float fast_exp2(float x) {
#if __has_builtin(__builtin_amdgcn_exp2f)
    return __builtin_amdgcn_exp2f(x);
#else
    return exp2f(x);
#endif
}

// ---------------- fp32 -> bf16 convert: x + all 4 weights, one launch ----
__global__ __launch_bounds__(256) void cvt_all(
    const float* __restrict__ x, const float* __restrict__ a,
    const float* __restrict__ b, const float* __restrict__ c,
    const float* __restrict__ d, unsigned short* __restrict__ ox,
    unsigned short* __restrict__ oa, unsigned short* __restrict__ ob,
    unsigned short* __restrict__ oc, unsigned short* __restrict__ od) {
    const int id = blockIdx.x * 256 + threadIdx.x;
    const float* src; unsigned short* dst; int sub;
    if (id < 2097152) {
        src = x; dst = ox; sub = id;
    } else {
        const int wi = id - 2097152;
        const int which = wi >> 18;
        sub = wi & 262143;
        if (which == 0)      { src = a; dst = oa; }
        else if (which == 1) { src = b; dst = ob; }
        else if (which == 2) { src = c; dst = oc; }
        else                 { src = d; dst = od; }
    }
    float4 v = ((const float4*)src)[sub];
    ushort4 o;
    o.x = f32_bf16(v.x); o.y = f32_bf16(v.y);
    o.z = f32_bf16(v.z); o.w = f32_bf16(v.w);
    ((ushort4*)dst)[sub] = o;
}

// ---------------- fused QKV GEMM: 256x256 8-phase counted-vmcnt ----------
// 8 waves (2M x 4N), BK=64, 128 KiB dynamic LDS:
//   lds[buf(2)][region(4): A-h0, A-h1, B-h0, B-h1][128*64 shorts]
// Per K-tile: 4 phases, each = one C-quadrant (16 MFMA, full K=64) and one
// half-tile stage (2x global_load_lds dwordx4).  One vmcnt(4) per tile
// boundary keeps 2 half-tiles in flight (never drains to 0 mid-loop).
// LDS swizzle: 16B-slot ^= (row&7) applied on global source col during
// staging AND on ds_read addr (rule: both-sides-or-neither with
// global_load_lds; dest stays lane-linear).
__global__ __launch_bounds__(512, 2) void gemm_qkv8(
    const unsigned short* __restrict__ A,
    const unsigned short* __restrict__ Wcat,
    const float* __restrict__ bq, const float* __restrict__ bk,
    const float* __restrict__ bv,
    unsigned short* __restrict__ qout, unsigned short* __restrict__ kout,
    unsigned short* __restrict__ vout) {
    extern __shared__ unsigned short lds[];

    const int tid  = threadIdx.x;
    const int wid  = tid >> 6;      // 0..7
    const int lane = tid & 63;
    const int quad = lane >> 4;     // 0..3
    const int lr   = lane & 15;
    const int wr   = wid >> 2;      // 0..1  (M)
    const int wc   = wid & 3;       // 0..3  (N)

    const int bm0 = blockIdx.y * 256;   // grid.y = 32
    const int bn0 = blockIdx.x * 256;   // grid.x = 12

    // staging: half-tile = 128 rows x 64 cols bf16 = 16KB = 2 calls x 8KB.
    // call c: wave w covers rows c*64 + w*8 + (lane>>3); lane-linear LDS.
    const int srow  = wid * 8 + (lane >> 3);            // 0..63
    const int scol  = ((lane & 7) ^ (lane >> 3)) * 8;   // swizzled src col
    const int sldso = wid * 512;                        // shorts

    // fragment read offsets (row&7 == lr&7 everywhere: bases are mult of 8)
    const int a_r   = wr * 64 + lr;
    const int b_r   = wc * 32 + lr;
    const int slot0 = (quad ^ (lr & 7)) * 8;            // ks=0, shorts
    const int slot1 = ((quad ^ 4) ^ (lr & 7)) * 8;      // ks=1

    f32x4 acc[8][4];
    const f32x4 zero = {0.f, 0.f, 0.f, 0.f};
#pragma unroll
    for (int i = 0; i < 8; ++i)
#pragma unroll
        for (int j = 0; j < 4; ++j) acc[i][j] = zero;

    short8 areg[4][2];
    short8 breg[2][2][2];

#define STG(S, BUF, REG, GB, GROW)                                          \
    do {                                                                    \
        if ((S) < 16) {                                                     \
            unsigned short* lb = lds + ((BUF) * 4 + (REG)) * 8192 + sldso;  \
            const unsigned short* gp =                                      \
                (GB) + (size_t)((GROW) + srow) * Cc + (S) * 64 + scol;      \
            ASYNC16(gp, lb);                                                \
            ASYNC16(gp + (size_t)64 * Cc, lb + 4096);                       \
        }                                                                   \
    } while (0)

#define LDA(mh)                                                             \
    do {                                                                    \
        const unsigned short* ab = bufb + (mh) * 8192;                      \
        _Pragma("unroll") for (int mf = 0; mf < 4; ++mf) {                  \
            areg[mf][0] = *(const short8*)(ab + (a_r + mf * 16) * 64 + slot0); \
            areg[mf][1] = *(const short8*)(ab + (a_r + mf * 16) * 64 + slot1); \
        }                                                                   \
    } while (0)

#define LDB(nh)                                                             \
    do {                                                                    \
        const unsigned short* bb = bufb + (2 + (nh)) * 8192;                \
        _Pragma("unroll") for (int nf = 0; nf < 2; ++nf) {                  \
            breg[nh][nf][0] = *(const short8*)(bb + (b_r + nf * 16) * 64 + slot0); \
            breg[nh][nf][1] = *(const short8*)(bb + (b_r + nf * 16) * 64 + slot1); \
        }                                                                   \
    } while (0)

#define MFMA_PHASE(mh, nh)                                                  \
    _Pragma("unroll") for (int mf = 0; mf < 4; ++mf)                        \
    _Pragma("unroll") for (int nf = 0; nf < 2; ++nf) {                      \
        acc[(mh)*4+mf][(nh)*2+nf] = __builtin_amdgcn_mfma_f32_16x16x32_bf16( \
            areg[mf][0], breg[nh][nf][0], acc[(mh)*4+mf][(nh)*2+nf], 0,0,0); \
        acc[(mh)*4+mf][(nh)*2+nf] = __builtin_amdgcn_mfma_f32_16x16x32_bf16( \
            areg[mf][1], breg[nh][nf][1], acc[(mh)*4+mf][(nh)*2+nf], 0,0,0); \
    }

// Stage stagger (race-free: each target region's last LDS read is >=1
// barrier before the stage issue; regs cached at p1/p2 cover p3/p4):
//   p1: (T+1, A-h1)  p2: (T+1, B-h1)  p3: (T+2, A-h0)  p4: (T+2, B-h0)
// vmcnt(WN) at p4 end: WN=4 forces tile T+1 fully resident, leaves the
// last 2 half-tiles (tile T+2) in flight.
#define TILE(T, BC, WN)                                                     \
    {                                                                       \
        const unsigned short* bufb = lds + (BC) * 32768;                    \
        LDA(0);                                                             \
        LDB(0);                                                             \
        STG((T) + 1, (BC) ^ 1, 1, A, bm0 + 128);                            \
        __builtin_amdgcn_s_barrier();                                       \
        asm volatile("s_waitcnt lgkmcnt(0)" ::: "memory");                  \
        __builtin_amdgcn_s_setprio(1);                                      \
        MFMA_PHASE(0, 0);                                                   \
        __builtin_amdgcn_s_setprio(0);                                      \
        __builtin_amdgcn_s_barrier();                                       \
        LDB(1);                                                             \
        STG((T) + 1, (BC) ^ 1, 3, Wcat, bn0 + 128);                         \
        __builtin_amdgcn_s_barrier();                                       \
        asm volatile("s_waitcnt lgkmcnt(0)" ::: "memory");                  \
        __builtin_amdgcn_s_setprio(1);                                      \
        MFMA_PHASE(0, 1);                                                   \
        __builtin_amdgcn_s_setprio(0);                                      \
        __builtin_amdgcn_s_barrier();                                       \
        LDA(1);                                                             \
        STG((T) + 2, (BC), 0, A, bm0);                                      \
        __builtin_amdgcn_s_barrier();                                       \
        asm volatile("s_waitcnt lgkmcnt(0)" ::: "memory");                  \
        __builtin_amdgcn_s_setprio(1);                                      \
        MFMA_PHASE(1, 0);                                                   \
        __builtin_amdgcn_s_setprio(0);                                      \
        __builtin_amdgcn_s_barrier();                                       \
        STG((T) + 2, (BC), 2, Wcat, bn0);                                   \
        __builtin_amdgcn_s_barrier();                                       \
        __builtin_amdgcn_s_setprio(1);                                      \
        MFMA_PHASE(1, 1);                                                   \
        __builtin_amdgcn_s_setprio(0);                                      \
        asm volatile("s_waitcnt vmcnt(" #WN ")" ::: "memory");              \
        __builtin_amdgcn_s_barrier();                                       \
    }

    // prologue: tile0 complete + tile1 {A-h0, B-h0}; wait tile0 (last 4 float)
    STG(0, 0, 0, A, bm0);
    STG(0, 0, 1, A, bm0 + 128);
    STG(0, 0, 2, Wcat, bn0);
    STG(0, 0, 3, Wcat, bn0 + 128);
    STG(1, 1, 0, A, bm0);
    STG(1, 1, 2, Wcat, bn0);
    asm volatile("s_waitcnt vmcnt(4)" ::: "memory");
    __builtin_amdgcn_s_barrier();

    for (int t2 = 0; t2 < 7; ++t2) {
        const int T0 = t2 * 2;
        TILE(T0, 0, 4);
        TILE(T0 + 1, 1, 4);
    }
    // T=14: its p3/p4 stages (tile 16) are skipped, so the steady-state
    // vmcnt(4) guarantee breaks -> drain fully here. T=15: no stages left.
    TILE(14, 0, 0);
    TILE(15, 1, 0);

#undef TILE
#undef MFMA_PHASE
#undef LDB
#undef LDA
#undef STG

    // epilogue: identical semantics to verified 128x128 kernel, re-indexed.
    const int which = bn0 >> 10;  // 0=q 1=k 2=v (256 | 1024, never straddles)
    const float* bias = (which == 0) ? bq : (which == 1) ? bk : bv;
    unsigned short* outp = (which == 0) ? qout : (which == 1) ? kout : vout;
    const float scale = (which == 0) ? 0.1803368801111204f : 1.0f;  // 0.125*log2e
    const bool vmode = (which == 2);
    const int nb = bn0 & 1023;

#pragma unroll
    for (int nh = 0; nh < 2; ++nh)
#pragma unroll
        for (int nf = 0; nf < 2; ++nf) {
            const int nl = nb + nh * 128 + wc * 32 + nf * 16 + lr;
            const float bvv = bias[nl];
            const int h = nl >> 6, hd = nl & 63;
#pragma unroll
            for (int mh = 0; mh < 2; ++mh)
#pragma unroll
                for (int mf = 0; mf < 4; ++mf) {
                    const f32x4 a = acc[mh * 4 + mf][nh * 2 + nf];
                    const int m0 = bm0 + mh * 128 + wr * 64 + mf * 16 + quad * 4;
                    const int b = m0 >> 11, t0 = m0 & 2047;
                    if (vmode) {
                        ushort4 pk;
                        pk.x = f32_bf16_rn(a[0] + bvv);
                        pk.y = f32_bf16_rn(a[1] + bvv);
                        pk.z = f32_bf16_rn(a[2] + bvv);
                        pk.w = f32_bf16_rn(a[3] + bvv);
                        *(ushort4*)(outp + (((size_t)(b * Hh + h)) * HDd + hd) * Tt + t0) = pk;
                    } else {
#pragma unroll
                        for (int r = 0; r < 4; ++r) {
                            outp[(((size_t)(b * Hh + h)) * Tt + t0 + r) * HDd + hd] =
                                f32_bf16_rn((a[r] + bvv) * scale);
                        }
                    }
                }
        }
}

// ---------------- output projection GEMM: 128x64 tiles, fp32 out ---------
// grid (16,64) = 1024 blocks -> 4 blocks/CU (512 = 2/CU starved).
__global__ __launch_bounds__(256) void gemm_proj(const unsigned short* __restrict__ A,
                                                 const unsigned short* __restrict__ W,
                                                 const float* __restrict__ bias,
                                                 float* __restrict__ out) {
    __shared__ unsigned short sA[2][128 * 32];
    __shared__ unsigned short sB[2][64 * 32];

    const int tid  = threadIdx.x;
    const int bm0  = blockIdx.y * 128;
    const int bn0  = blockIdx.x * 64;
    const int wid  = tid >> 6;
    const int lane = tid & 63;
    const int quad = lane >> 4;
    const int lr   = lane & 15;
    const int wm   = (wid & 1) * 64;
    const int wn   = (wid >> 1) * 32;

    const int sr   = lane >> 2;
    const int scol = (lane & 3) * 8;
    const int row0 = wid * 16 + sr;          // A rows 0..63
    const int row1 = 64 + wid * 16 + sr;     // A rows 64..127; also B rows 0..63
    const int lo0  = wid * 512;
    const int lo1  = (4 + wid) * 512;

    f32x4 acc[4][2];
    f32x4 zero = {0.f, 0.f, 0.f, 0.f};
#pragma unroll
    for (int i = 0; i < 4; i++)
#pragma unroll
        for (int j = 0; j < 2; j++) acc[i][j] = zero;

    ASYNC16(A + (size_t)(bm0 + row0) * Cc + scol, sA[0] + lo0);
    ASYNC16(A + (size_t)(bm0 + row1) * Cc + scol, sA[0] + lo1);
    ASYNC16(W + (size_t)(bn0 + row0) * Cc + scol, sB[0] + lo0);
    __syncthreads();

    for (int kt = 0; kt < Cc / 32; ++kt) {
        const int cur = kt & 1, nxt = cur ^ 1;
        if (kt + 1 < Cc / 32) {
            const int kb = (kt + 1) * 32;
            ASYNC16(A + (size_t)(bm0 + row0) * Cc + kb + scol, sA[nxt] + lo0);
            ASYNC16(A + (size_t)(bm0 + row1) * Cc + kb + scol, sA[nxt] + lo1);
            ASYNC16(W + (size_t)(bn0 + row0) * Cc + kb + scol, sB[nxt] + lo0);
        }

        short8 af[4], bf[2];
#pragma unroll
        for (int i = 0; i < 4; i++)
            af[i] = *(const short8*)(sA[cur] + (wm + i * 16 + lr) * 32 + quad * 8);
#pragma unroll
        for (int j = 0; j < 2; j++)
            bf[j] = *(const short8*)(sB[cur] + (wn + j * 16 + lr) * 32 + quad * 8);
#pragma unroll
        for (int i = 0; i < 4; i++)
#pragma unroll
            for (int j = 0; j < 2; j++)
                acc[i][j] = __builtin_amdgcn_mfma_f32_16x16x32_bf16(af[i], bf[j], acc[i][j], 0, 0, 0);

        __syncthreads();
    }

#pragma unroll
    for (int j = 0; j < 2; j++) {
        const int n = bn0 + wn + j * 16 + lr;
        const float bvv = bias[n];
#pragma unroll
        for (int i = 0; i < 4; i++)
#pragma unroll
            for (int r = 0; r < 4; r++) {
                const int m = bm0 + wm + i * 16 + quad * 4 + r;
                out[(size_t)m * Cc + n] = acc[i][j][r] + bvv;
            }
    }
}

// ---------------- flash attention: round-4-proven config -----------------
// grid (8,64): block handles Q-blocks qt=x and qt=15-x -> exactly 34
// tile-iters per block (perfect balance). K/V double-buffered in LDS with
// register-relay prefetch: ONE __syncthreads per tile. Per-strip sP.
// LDS leading dims are 72 shorts = 144 B (multiple of 16 B: b128-aligned;
// 70 is NOT and cost 2.7x in round 8). Unnormalized log2-domain softmax.
__global__ __launch_bounds__(256) void attn(const unsigned short* __restrict__ q,
                                            const unsigned short* __restrict__ k,
                                            const unsigned short* __restrict__ vt,
                                            unsigned short* __restrict__ y) {
    __shared__ unsigned short sK[2][64 * 72];
    __shared__ unsigned short sV[2][64 * 72];
    __shared__ unsigned short sP[4][2][16 * 72];  // [wave][strip]

    const int tid  = threadIdx.x;
    const int wid  = tid >> 6;
    const int lane = tid & 63;
    const int quad = lane >> 4;
    const int lr   = lane & 15;

    const int bh = blockIdx.y;
    const size_t headq = (size_t)bh * Tt * HDd;
    const unsigned short* kg = k + headq;
    const unsigned short* vg = vt + headq;
    const int b = bh >> 4, h = bh & 15;

    const int rs0 = tid >> 3;
    const int es  = (tid & 7) * 8;

    f32x4 zero = {0.f, 0.f, 0.f, 0.f};

    for (int pass = 0; pass < 2; ++pass) {
        const int qt = pass ? (15 - blockIdx.x) : blockIdx.x;
        const int qb = qt * 128;
        const int ntiles = 2 * qt + 2;

        short8 qf[2][2];
#pragma unroll
        for (int s = 0; s < 2; s++) {
            const unsigned short* qp =
                q + headq + (size_t)(qb + s * 64 + wid * 16 + lr) * HDd;
            qf[s][0] = *(const short8*)(qp + quad * 8);
            qf[s][1] = *(const short8*)(qp + 32 + quad * 8);
        }

        f32x4 o[2][4];
        float l_run[2][4];
#pragma unroll
        for (int s = 0; s < 2; s++)
#pragma unroll
            for (int i = 0; i < 4; i++) { o[s][i] = zero; l_run[s][i] = 0.f; }

        // tile 0 -> regs -> buf0
        uint4 ka0 = *(const uint4*)(kg + (size_t)(rs0)      * HDd + es);
        uint4 ka1 = *(const uint4*)(kg + (size_t)(rs0 + 32) * HDd + es);
        uint4 va0 = *(const uint4*)(vg + (size_t)(rs0)      * Tt + es);
        uint4 va1 = *(const uint4*)(vg + (size_t)(rs0 + 32) * Tt + es);
        *(uint4*)(sK[0] + rs0 * 72 + es)        = ka0;
        *(uint4*)(sK[0] + (rs0 + 32) * 72 + es) = ka1;
        *(uint4*)(sV[0] + rs0 * 72 + es)        = va0;
        *(uint4*)(sV[0] + (rs0 + 32) * 72 + es) = va1;
        __syncthreads();
        {
            const int kb2 = 64;
            ka0 = *(const uint4*)(kg + (size_t)(kb2 + rs0)      * HDd + es);
            ka1 = *(const uint4*)(kg + (size_t)(kb2 + rs0 + 32) * HDd + es);
            va0 = *(const uint4*)(vg + (size_t)(rs0)      * Tt + kb2 + es);
            va1 = *(const uint4*)(vg + (size_t)(rs0 + 32) * Tt + kb2 + es);
        }

        for (int kt = 0; kt < ntiles; ++kt) {
            const int cur = kt & 1, nxt = cur ^ 1;
            if (kt + 1 < ntiles) {
                *(uint4*)(sK[nxt] + rs0 * 72 + es)        = ka0;
                *(uint4*)(sK[nxt] + (rs0 + 32) * 72 + es) = ka1;
                *(uint4*)(sV[nxt] + rs0 * 72 + es)        = va0;
                *(uint4*)(sV[nxt] + (rs0 + 32) * 72 + es) = va1;
            }
            if (kt + 2 < ntiles) {
                const int kb2 = (kt + 2) * 64;
                ka0 = *(const uint4*)(kg + (size_t)(kb2 + rs0)      * HDd + es);
                ka1 = *(const uint4*)(kg + (size_t)(kb2 + rs0 + 32) * HDd + es);
                va0 = *(const uint4*)(vg + (size_t)(rs0)      * Tt + kb2 + es);
                va1 = *(const uint4*)(vg + (size_t)(rs0 + 32) * Tt + kb2 + es);
            }

            const unsigned short* bK = sK[cur];
            const unsigned short* bV = sV[cur];
            const int s_lo = (kt == ntiles - 1) ? 1 : 0;  // strip0 skips last tile

            // phase 1: QK^T for active strips
            f32x4 sc[2][4];
#pragma unroll
            for (int s = 0; s < 2; s++) {
                if (s < s_lo) continue;
#pragma unroll
                for (int nt = 0; nt < 4; nt++) {
                    short8 b0 = *(const short8*)(bK + (nt * 16 + lr) * 72 + quad * 8);
                    short8 b1 = *(const short8*)(bK + (nt * 16 + lr) * 72 + 32 + quad * 8);
                    f32x4 a = zero;
                    a = __builtin_amdgcn_mfma_f32_16x16x32_bf16(qf[s][0], b0, a, 0, 0, 0);
                    a = __builtin_amdgcn_mfma_f32_16x16x32_bf16(qf[s][1], b1, a, 0, 0, 0);
                    sc[s][nt] = a;
                }
            }

            // phase 2: mask diag, exp2, accumulate l, pack P to LDS
#pragma unroll
            for (int s = 0; s < 2; s++) {
                if (s < s_lo) continue;
                if (kt == ntiles - 2 + s) {
#pragma unroll
                    for (int nt = 0; nt < 4; nt++)
#pragma unroll
                        for (int r = 0; r < 4; r++)
                            sc[s][nt][r] = (nt * 16 + lr <= wid * 16 + quad * 4 + r)
                                               ? sc[s][nt][r] : -INFINITY;
                }
                unsigned short* sPw = sP[wid][s];
#pragma unroll
                for (int nt = 0; nt < 4; nt++)
#pragma unroll
                    for (int r = 0; r < 4; r++) {
                        const float p = fast_exp2(sc[s][nt][r]);
                        l_run[s][r] += p;
                        sPw[(quad * 4 + r) * 72 + nt * 16 + lr] = f32_bf16_rn(p);
                    }
            }

            // phase 3: P (A-layout) @ V
#pragma unroll
            for (int s = 0; s < 2; s++) {
                if (s < s_lo) continue;
                const unsigned short* sPw = sP[wid][s];
                short8 pa0 = *(const short8*)(sPw + lr * 72 + quad * 8);
                short8 pa1 = *(const short8*)(sPw + lr * 72 + 32 + quad * 8);
#pragma unroll
                for (int nt = 0; nt < 4; nt++) {
                    short8 vb0 = *(const short8*)(bV + (nt * 16 + lr) * 72 + quad * 8);
                    short8 vb1 = *(const short8*)(bV + (nt * 16 + lr) * 72 + 32 + quad * 8);
                    o[s][nt] = __builtin_amdgcn_mfma_f32_16x16x32_bf16(pa0, vb0, o[s][nt], 0, 0, 0);
                    o[s][nt] = __builtin_amdgcn_mfma_f32_16x16x32_bf16(pa1, vb1, o[s][nt], 0, 0, 0);
                }
            }

            __syncthreads();
        }

#pragma unroll
        for (int s = 0; s < 2; s++) {
#pragma unroll
            for (int r = 0; r < 4; r++) {
                float ls = l_run[s][r];
                ls += __shfl_xor(ls, 1);
                ls += __shfl_xor(ls, 2);
                ls += __shfl_xor(ls, 4);
                ls += __shfl_xor(ls, 8);
                const float inv = 1.0f / ls;
                const int t = qb + s * 64 + wid * 16 + quad * 4 + r;
#pragma unroll
                for (int nt = 0; nt < 4; nt++) {
                    const int dim = nt * 16 + lr;
                    y[((size_t)(b * Tt + t)) * Cc + h * HDd + dim] =
                        f32_bf16_rn(o[s][nt][r] * inv);
                }
            }
        }
    }
}

// ---------------- launch ----------------
extern "C" void kernel_launch(void* const* d_in, const int* in_sizes, int n_in,
                              void* d_out, int out_size, void* d_ws, size_t ws_size,
                              hipStream_t stream) {
    const float* x  = (const float*)d_in[0];
    const float* Wk = (const float*)d_in[1];
    const float* bk = (const float*)d_in[2];
    const float* Wq = (const float*)d_in[3];
    const float* bq = (const float*)d_in[4];
    const float* Wv = (const float*)d_in[5];
    const float* bv = (const float*)d_in[6];
    const float* Wp = (const float*)d_in[7];
    const float* bp = (const float*)d_in[8];
    float* out = (float*)d_out;

    char* ws = (char*)d_ws;
    size_t off = 0;
    auto alloc = [&](size_t bytes) { char* p = ws + off; off += bytes; return p; };
    const size_t MK = (size_t)8192 * 1024;
    const size_t NK = (size_t)1024 * 1024;
    unsigned short* xb   = (unsigned short*)alloc(MK * 2);
    unsigned short* Wcat = (unsigned short*)alloc(3 * NK * 2);  // q|k|v contiguous
    unsigned short* Wqb  = Wcat;
    unsigned short* Wkb  = Wcat + NK;
    unsigned short* Wvb  = Wcat + 2 * NK;
    unsigned short* Wpb  = (unsigned short*)alloc(NK * 2);
    unsigned short* qh   = (unsigned short*)alloc(MK * 2);  // [B,H,T,HD], pre-scaled
    unsigned short* kh   = (unsigned short*)alloc(MK * 2);  // [B,H,T,HD]
    unsigned short* vth  = (unsigned short*)alloc(MK * 2);  // [B,H,HD,T]
    unsigned short* ya   = (unsigned short*)alloc(MK * 2);  // [B,T,C]

    // one-time: allow 128 KiB dynamic LDS for the 8-phase GEMM
    // (not a stream op; safe under graph capture, guarded anyway)
    static bool lds_attr_set = false;
    if (!lds_attr_set) {
        (void)hipFuncSetAttribute((const void*)gemm_qkv8,
                                  hipFuncAttributeMaxDynamicSharedMemorySize,
                                  131072);
        lds_attr_set = true;
    }

    cvt_all<<<12288, 256, 0, stream>>>(x, Wq, Wk, Wv, Wp, xb, Wqb, Wkb, Wvb, Wpb);

    gemm_qkv8<<<dim3(12, 32), 512, 131072, stream>>>(xb, Wcat, bq, bk, bv, qh, kh, vth);

    attn<<<dim3(8, 64), 256, 0, stream>>>(qh, kh, vth, ya);

    gemm_proj<<<dim3(16, 64), 256, 0, stream>>>(ya, Wpb, bp, out);
}

// Round 2
// 265.409 us; speedup vs baseline: 1.0523x; 1.0113x over previous
//
#include <hip/hip_runtime.h>
#include <hip/hip_bf16.h>
#include <cmath>

#define Tt 2048
#define Cc 1024
#define Hh 16
#define HDd 64

typedef __attribute__((ext_vector_type(8))) short short8;
typedef __attribute__((ext_vector_type(4))) float f32x4;

// async global->LDS, 16B per lane; lds base must be wave-uniform
#define ASYNC16(gp, lp)                                       \
    __builtin_amdgcn_global_load_lds(                         \
        (const __attribute__((address_space(1))) void*)(gp),  \
        (__attribute__((address_space(3))) void*)(lp), 16, 0, 0)

__device__ __forceinline__ unsigned short f32_bf16(float f) {
    unsigned u = __float_as_uint(f);
    u += 0x7FFF + ((u >> 16) & 1);
    return (unsigned short)(u >> 16);
}
// 2-op round-to-nearest (ties away) — fine for finite values
__device__ __forceinline__ unsigned short f32_bf16_rn(float f) {
    return (unsigned short)((__float_as_uint(f) + 0x8000u) >> 16);
}
__device__ __forceinline__ float fast_exp2(float x) {
#if __has_builtin(__builtin_amdgcn_exp2f)
    return __builtin_amdgcn_exp2f(x);
#else
    return exp2f(x);
#endif
}

// ---------------- fp32 -> bf16 convert: x + all 4 weights, one launch ----
__global__ __launch_bounds__(256) void cvt_all(
    const float* __restrict__ x, const float* __restrict__ a,
    const float* __restrict__ b, const float* __restrict__ c,
    const float* __restrict__ d, unsigned short* __restrict__ ox,
    unsigned short* __restrict__ oa, unsigned short* __restrict__ ob,
    unsigned short* __restrict__ oc, unsigned short* __restrict__ od) {
    const int id = blockIdx.x * 256 + threadIdx.x;
    const float* src; unsigned short* dst; int sub;
    if (id < 2097152) {
        src = x; dst = ox; sub = id;
    } else {
        const int wi = id - 2097152;
        const int which = wi >> 18;
        sub = wi & 262143;
        if (which == 0)      { src = a; dst = oa; }
        else if (which == 1) { src = b; dst = ob; }
        else if (which == 2) { src = c; dst = oc; }
        else                 { src = d; dst = od; }
    }
    float4 v = ((const float4*)src)[sub];
    ushort4 o;
    o.x = f32_bf16(v.x); o.y = f32_bf16(v.y);
    o.z = f32_bf16(v.z); o.w = f32_bf16(v.w);
    ((ushort4*)dst)[sub] = o;
}

// ---------------- fused QKV GEMM: 256x256 8-phase counted-vmcnt ----------
// 8 waves (2M x 4N), BK=64, 128 KiB dynamic LDS:
//   lds[buf(2)][region(4): A-h0, A-h1, B-h0, B-h1][128*64 shorts]
// Per K-tile: 4 phases, each = one C-quadrant (16 MFMA, full K=64) and one
// half-tile stage (2x global_load_lds dwordx4).  One vmcnt(4) per tile
// boundary keeps 2 half-tiles in flight (never drains to 0 mid-loop).
// LDS swizzle: 16B-slot ^= (row&7) applied on global source col during
// staging AND on ds_read addr (rule: both-sides-or-neither with
// global_load_lds; dest stays lane-linear).
__global__ __launch_bounds__(512, 2) void gemm_qkv8(
    const unsigned short* __restrict__ A,
    const unsigned short* __restrict__ Wcat,
    const float* __restrict__ bq, const float* __restrict__ bk,
    const float* __restrict__ bv,
    unsigned short* __restrict__ qout, unsigned short* __restrict__ kout,
    unsigned short* __restrict__ vout) {
    extern __shared__ unsigned short lds[];

    const int tid  = threadIdx.x;
    const int wid  = tid >> 6;      // 0..7
    const int lane = tid & 63;
    const int quad = lane >> 4;     // 0..3
    const int lr   = lane & 15;
    const int wr   = wid >> 2;      // 0..1  (M)
    const int wc   = wid & 3;       // 0..3  (N)

    const int bm0 = blockIdx.y * 256;   // grid.y = 32
    const int bn0 = blockIdx.x * 256;   // grid.x = 12

    // staging: half-tile = 128 rows x 64 cols bf16 = 16KB = 2 calls x 8KB.
    // call c: wave w covers rows c*64 + w*8 + (lane>>3); lane-linear LDS.
    const int srow  = wid * 8 + (lane >> 3);            // 0..63
    const int scol  = ((lane & 7) ^ (lane >> 3)) * 8;   // swizzled src col
    const int sldso = wid * 512;                        // shorts

    // fragment read offsets (row&7 == lr&7 everywhere: bases are mult of 8)
    const int a_r   = wr * 64 + lr;
    const int b_r   = wc * 32 + lr;
    const int slot0 = (quad ^ (lr & 7)) * 8;            // ks=0, shorts
    const int slot1 = ((quad ^ 4) ^ (lr & 7)) * 8;      // ks=1

    f32x4 acc[8][4];
    const f32x4 zero = {0.f, 0.f, 0.f, 0.f};
#pragma unroll
    for (int i = 0; i < 8; ++i)
#pragma unroll
        for (int j = 0; j < 4; ++j) acc[i][j] = zero;

    short8 areg[4][2];
    short8 breg[2][2][2];

#define STG(S, BUF, REG, GB, GROW)                                          \
    do {                                                                    \
        if ((S) < 16) {                                                     \
            unsigned short* lb = lds + ((BUF) * 4 + (REG)) * 8192 + sldso;  \
            const unsigned short* gp =                                      \
                (GB) + (size_t)((GROW) + srow) * Cc + (S) * 64 + scol;      \
            ASYNC16(gp, lb);                                                \
            ASYNC16(gp + (size_t)64 * Cc, lb + 4096);                       \
        }                                                                   \
    } while (0)

#define LDA(mh)                                                             \
    do {                                                                    \
        const unsigned short* ab = bufb + (mh) * 8192;                      \
        _Pragma("unroll") for (int mf = 0; mf < 4; ++mf) {                  \
            areg[mf][0] = *(const short8*)(ab + (a_r + mf * 16) * 64 + slot0); \
            areg[mf][1] = *(const short8*)(ab + (a_r + mf * 16) * 64 + slot1); \
        }                                                                   \
    } while (0)

#define LDB(nh)                                                             \
    do {                                                                    \
        const unsigned short* bb = bufb + (2 + (nh)) * 8192;                \
        _Pragma("unroll") for (int nf = 0; nf < 2; ++nf) {                  \
            breg[nh][nf][0] = *(const short8*)(bb + (b_r + nf * 16) * 64 + slot0); \
            breg[nh][nf][1] = *(const short8*)(bb + (b_r + nf * 16) * 64 + slot1); \
        }                                                                   \
    } while (0)

#define MFMA_PHASE(mh, nh)                                                  \
    _Pragma("unroll") for (int mf = 0; mf < 4; ++mf)                        \
    _Pragma("unroll") for (int nf = 0; nf < 2; ++nf) {                      \
        acc[(mh)*4+mf][(nh)*2+nf] = __builtin_amdgcn_mfma_f32_16x16x32_bf16( \
            areg[mf][0], breg[nh][nf][0], acc[(mh)*4+mf][(nh)*2+nf], 0,0,0); \
        acc[(mh)*4+mf][(nh)*2+nf] = __builtin_amdgcn_mfma_f32_16x16x32_bf16( \
            areg[mf][1], breg[nh][nf][1], acc[(mh)*4+mf][(nh)*2+nf], 0,0,0); \
    }

// Stage stagger (race-free: each target region's last LDS read is >=1
// barrier before the stage issue; regs cached at p1/p2 cover p3/p4):
//   p1: (T+1, A-h1)  p2: (T+1, B-h1)  p3: (T+2, A-h0)  p4: (T+2, B-h0)
// vmcnt(WN) at p4 end: WN=4 forces tile T+1 fully resident, leaves the
// last 2 half-tiles (tile T+2) in flight.
#define TILE(T, BC, WN)                                                     \
    {                                                                       \
        const unsigned short* bufb = lds + (BC) * 32768;                    \
        LDA(0);                                                             \
        LDB(0);                                                             \
        STG((T) + 1, (BC) ^ 1, 1, A, bm0 + 128);                            \
        __builtin_amdgcn_s_barrier();                                       \
        asm volatile("s_waitcnt lgkmcnt(0)" ::: "memory");                  \
        __builtin_amdgcn_s_setprio(1);                                      \
        MFMA_PHASE(0, 0);                                                   \
        __builtin_amdgcn_s_setprio(0);                                      \
        __builtin_amdgcn_s_barrier();                                       \
        LDB(1);                                                             \
        STG((T) + 1, (BC) ^ 1, 3, Wcat, bn0 + 128);                         \
        __builtin_amdgcn_s_barrier();                                       \
        asm volatile("s_waitcnt lgkmcnt(0)" ::: "memory");                  \
        __builtin_amdgcn_s_setprio(1);                                      \
        MFMA_PHASE(0, 1);                                                   \
        __builtin_amdgcn_s_setprio(0);                                      \
        __builtin_amdgcn_s_barrier();                                       \
        LDA(1);                                                             \
        STG((T) + 2, (BC), 0, A, bm0);                                      \
        __builtin_amdgcn_s_barrier();                                       \
        asm volatile("s_waitcnt lgkmcnt(0)" ::: "memory");                  \
        __builtin_amdgcn_s_setprio(1);                                      \
        MFMA_PHASE(1, 0);                                                   \
        __builtin_amdgcn_s_setprio(0);                                      \
        __builtin_amdgcn_s_barrier();                                       \
        STG((T) + 2, (BC), 2, Wcat, bn0);                                   \
        __builtin_amdgcn_s_barrier();                                       \
        __builtin_amdgcn_s_setprio(1);                                      \
        MFMA_PHASE(1, 1);                                                   \
        __builtin_amdgcn_s_setprio(0);                                      \
        asm volatile("s_waitcnt vmcnt(" #WN ")" ::: "memory");              \
        __builtin_amdgcn_s_barrier();                                       \
    }

    // prologue: tile0 complete + tile1 {A-h0, B-h0}; wait tile0 (last 4 float)
    STG(0, 0, 0, A, bm0);
    STG(0, 0, 1, A, bm0 + 128);
    STG(0, 0, 2, Wcat, bn0);
    STG(0, 0, 3, Wcat, bn0 + 128);
    STG(1, 1, 0, A, bm0);
    STG(1, 1, 2, Wcat, bn0);
    asm volatile("s_waitcnt vmcnt(4)" ::: "memory");
    __builtin_amdgcn_s_barrier();

    for (int t2 = 0; t2 < 7; ++t2) {
        const int T0 = t2 * 2;
        TILE(T0, 0, 4);
        TILE(T0 + 1, 1, 4);
    }
    // T=14: its p3/p4 stages (tile 16) are skipped, so the steady-state
    // vmcnt(4) guarantee breaks -> drain fully here. T=15: no stages left.
    TILE(14, 0, 0);
    TILE(15, 1, 0);

#undef TILE
#undef MFMA_PHASE
#undef LDB
#undef LDA
#undef STG

    // epilogue: identical semantics to verified 128x128 kernel, re-indexed.
    const int which = bn0 >> 10;  // 0=q 1=k 2=v (256 | 1024, never straddles)
    const float* bias = (which == 0) ? bq : (which == 1) ? bk : bv;
    unsigned short* outp = (which == 0) ? qout : (which == 1) ? kout : vout;
    const float scale = (which == 0) ? 0.1803368801111204f : 1.0f;  // 0.125*log2e
    const bool vmode = (which == 2);
    const int nb = bn0 & 1023;

#pragma unroll
    for (int nh = 0; nh < 2; ++nh)
#pragma unroll
        for (int nf = 0; nf < 2; ++nf) {
            const int nl = nb + nh * 128 + wc * 32 + nf * 16 + lr;
            const float bvv = bias[nl];
            const int h = nl >> 6, hd = nl & 63;
#pragma unroll
            for (int mh = 0; mh < 2; ++mh)
#pragma unroll
                for (int mf = 0; mf < 4; ++mf) {
                    const f32x4 a = acc[mh * 4 + mf][nh * 2 + nf];
                    const int m0 = bm0 + mh * 128 + wr * 64 + mf * 16 + quad * 4;
                    const int b = m0 >> 11, t0 = m0 & 2047;
                    if (vmode) {
                        ushort4 pk;
                        pk.x = f32_bf16_rn(a[0] + bvv);
                        pk.y = f32_bf16_rn(a[1] + bvv);
                        pk.z = f32_bf16_rn(a[2] + bvv);
                        pk.w = f32_bf16_rn(a[3] + bvv);
                        *(ushort4*)(outp + (((size_t)(b * Hh + h)) * HDd + hd) * Tt + t0) = pk;
                    } else {
#pragma unroll
                        for (int r = 0; r < 4; ++r) {
                            outp[(((size_t)(b * Hh + h)) * Tt + t0 + r) * HDd + hd] =
                                f32_bf16_rn((a[r] + bvv) * scale);
                        }
                    }
                }
        }
}

// ---------------- output projection GEMM: 128x64 tiles, fp32 out ---------
// grid (16,64) = 1024 blocks -> 4 blocks/CU (512 = 2/CU starved).
__global__ __launch_bounds__(256) void gemm_proj(const unsigned short* __restrict__ A,
                                                 const unsigned short* __restrict__ W,
                                                 const float* __restrict__ bias,
                                                 float* __restrict__ out) {
    __shared__ unsigned short sA[2][128 * 32];
    __shared__ unsigned short sB[2][64 * 32];

    const int tid  = threadIdx.x;
    const int bm0  = blockIdx.y * 128;
    const int bn0  = blockIdx.x * 64;
    const int wid  = tid >> 6;
    const int lane = tid & 63;
    const int quad = lane >> 4;
    const int lr   = lane & 15;
    const int wm   = (wid & 1) * 64;
    const int wn   = (wid >> 1) * 32;

    const int sr   = lane >> 2;
    const int scol = (lane & 3) * 8;
    const int row0 = wid * 16 + sr;          // A rows 0..63
    const int row1 = 64 + wid * 16 + sr;     // A rows 64..127; also B rows 0..63
    const int lo0  = wid * 512;
    const int lo1  = (4 + wid) * 512;

    f32x4 acc[4][2];
    f32x4 zero = {0.f, 0.f, 0.f, 0.f};
#pragma unroll
    for (int i = 0; i < 4; i++)
#pragma unroll
        for (int j = 0; j < 2; j++) acc[i][j] = zero;

    ASYNC16(A + (size_t)(bm0 + row0) * Cc + scol, sA[0] + lo0);
    ASYNC16(A + (size_t)(bm0 + row1) * Cc + scol, sA[0] + lo1);
    ASYNC16(W + (size_t)(bn0 + row0) * Cc + scol, sB[0] + lo0);
    __syncthreads();

    for (int kt = 0; kt < Cc / 32; ++kt) {
        const int cur = kt & 1, nxt = cur ^ 1;
        if (kt + 1 < Cc / 32) {
            const int kb = (kt + 1) * 32;
            ASYNC16(A + (size_t)(bm0 + row0) * Cc + kb + scol, sA[nxt] + lo0);
            ASYNC16(A + (size_t)(bm0 + row1) * Cc + kb + scol, sA[nxt] + lo1);
            ASYNC16(W + (size_t)(bn0 + row0) * Cc + kb + scol, sB[nxt] + lo0);
        }

        short8 af[4], bf[2];
#pragma unroll
        for (int i = 0; i < 4; i++)
            af[i] = *(const short8*)(sA[cur] + (wm + i * 16 + lr) * 32 + quad * 8);
#pragma unroll
        for (int j = 0; j < 2; j++)
            bf[j] = *(const short8*)(sB[cur] + (wn + j * 16 + lr) * 32 + quad * 8);
#pragma unroll
        for (int i = 0; i < 4; i++)
#pragma unroll
            for (int j = 0; j < 2; j++)
                acc[i][j] = __builtin_amdgcn_mfma_f32_16x16x32_bf16(af[i], bf[j], acc[i][j], 0, 0, 0);

        __syncthreads();
    }

#pragma unroll
    for (int j = 0; j < 2; j++) {
        const int n = bn0 + wn + j * 16 + lr;
        const float bvv = bias[n];
#pragma unroll
        for (int i = 0; i < 4; i++)
#pragma unroll
            for (int r = 0; r < 4; r++) {
                const int m = bm0 + wm + i * 16 + quad * 4 + r;
                out[(size_t)m * Cc + n] = acc[i][j][r] + bvv;
            }
    }
}

// ---------------- flash attention ----------------------------------------
// grid (8,64). XCD-aware remap: head = 8*blockIdx.x + (blockIdx.y&7),
// qx = blockIdx.y>>3.  Linear block id = x + 8y -> XCD = x, so all 8
// q-chunk blocks of a head share one XCD: per-XCD K/V working set =
// 8 heads x 512 KB = 4 MB = L2 size (was: every XCD streamed all 64 heads).
// Block handles Q-blocks qt=qx and qt=15-qx -> exactly 34 tile-iters per
// block (perfect balance). K/V double-buffered in LDS with register-relay
// prefetch: ONE __syncthreads per tile. K/V fragments hoisted to registers
// ONCE per tile and shared by both strips (halves ds_read_b128 traffic —
// LDS bytes were the dominant cost: ~176 KB/block-tile ≈ 44 µs at the
// 69 TB/s LDS ceiling). setprio(1) around MFMA clusters (T5).
// LDS leading dims are 72 shorts = 144 B (multiple of 16 B: b128-aligned).
// Unnormalized log2-domain softmax.
__global__ __launch_bounds__(256) void attn(const unsigned short* __restrict__ q,
                                            const unsigned short* __restrict__ k,
                                            const unsigned short* __restrict__ vt,
                                            unsigned short* __restrict__ y) {
    __shared__ unsigned short sK[2][64 * 72];
    __shared__ unsigned short sV[2][64 * 72];
    __shared__ unsigned short sP[4][2][16 * 72];  // [wave][strip]

    const int tid  = threadIdx.x;
    const int wid  = tid >> 6;
    const int lane = tid & 63;
    const int quad = lane >> 4;
    const int lr   = lane & 15;

    // XCD-aware remap (see header comment)
    const int bh = blockIdx.x * 8 + (blockIdx.y & 7);
    const int qx = blockIdx.y >> 3;
    const size_t headq = (size_t)bh * Tt * HDd;
    const unsigned short* kg = k + headq;
    const unsigned short* vg = vt + headq;
    const int b = bh >> 4, h = bh & 15;

    const int rs0 = tid >> 3;
    const int es  = (tid & 7) * 8;

    f32x4 zero = {0.f, 0.f, 0.f, 0.f};

    for (int pass = 0; pass < 2; ++pass) {
        const int qt = pass ? (15 - qx) : qx;
        const int qb = qt * 128;
        const int ntiles = 2 * qt + 2;

        short8 qf[2][2];
#pragma unroll
        for (int s = 0; s < 2; s++) {
            const unsigned short* qp =
                q + headq + (size_t)(qb + s * 64 + wid * 16 + lr) * HDd;
            qf[s][0] = *(const short8*)(qp + quad * 8);
            qf[s][1] = *(const short8*)(qp + 32 + quad * 8);
        }

        f32x4 o[2][4];
        float l_run[2][4];
#pragma unroll
        for (int s = 0; s < 2; s++)
#pragma unroll
            for (int i = 0; i < 4; i++) { o[s][i] = zero; l_run[s][i] = 0.f; }

        // tile 0 -> regs -> buf0
        uint4 ka0 = *(const uint4*)(kg + (size_t)(rs0)      * HDd + es);
        uint4 ka1 = *(const uint4*)(kg + (size_t)(rs0 + 32) * HDd + es);
        uint4 va0 = *(const uint4*)(vg + (size_t)(rs0)      * Tt + es);
        uint4 va1 = *(const uint4*)(vg + (size_t)(rs0 + 32) * Tt + es);
        *(uint4*)(sK[0] + rs0 * 72 + es)        = ka0;
        *(uint4*)(sK[0] + (rs0 + 32) * 72 + es) = ka1;
        *(uint4*)(sV[0] + rs0 * 72 + es)        = va0;
        *(uint4*)(sV[0] + (rs0 + 32) * 72 + es) = va1;
        __syncthreads();
        {
            const int kb2 = 64;
            ka0 = *(const uint4*)(kg + (size_t)(kb2 + rs0)      * HDd + es);
            ka1 = *(const uint4*)(kg + (size_t)(kb2 + rs0 + 32) * HDd + es);
            va0 = *(const uint4*)(vg + (size_t)(rs0)      * Tt + kb2 + es);
            va1 = *(const uint4*)(vg + (size_t)(rs0 + 32) * Tt + kb2 + es);
        }

        for (int kt = 0; kt < ntiles; ++kt) {
            const int cur = kt & 1, nxt = cur ^ 1;
            if (kt + 1 < ntiles) {
                *(uint4*)(sK[nxt] + rs0 * 72 + es)        = ka0;
                *(uint4*)(sK[nxt] + (rs0 + 32) * 72 + es) = ka1;
                *(uint4*)(sV[nxt] + rs0 * 72 + es)        = va0;
                *(uint4*)(sV[nxt] + (rs0 + 32) * 72 + es) = va1;
            }
            if (kt + 2 < ntiles) {
                const int kb2 = (kt + 2) * 64;
                ka0 = *(const uint4*)(kg + (size_t)(kb2 + rs0)      * HDd + es);
                ka1 = *(const uint4*)(kg + (size_t)(kb2 + rs0 + 32) * HDd + es);
                va0 = *(const uint4*)(vg + (size_t)(rs0)      * Tt + kb2 + es);
                va1 = *(const uint4*)(vg + (size_t)(rs0 + 32) * Tt + kb2 + es);
            }

            const unsigned short* bK = sK[cur];
            const unsigned short* bV = sV[cur];
            const int s_lo = (kt == ntiles - 1) ? 1 : 0;  // strip0 skips last tile

            // K fragments: read ONCE, shared by both strips
            short8 kf[4][2];
#pragma unroll
            for (int nt = 0; nt < 4; nt++) {
                kf[nt][0] = *(const short8*)(bK + (nt * 16 + lr) * 72 + quad * 8);
                kf[nt][1] = *(const short8*)(bK + (nt * 16 + lr) * 72 + 32 + quad * 8);
            }

            // phase 1: QK^T for active strips
            f32x4 sc[2][4];
            __builtin_amdgcn_s_setprio(1);
#pragma unroll
            for (int s = 0; s < 2; s++) {
                if (s < s_lo) continue;
#pragma unroll
                for (int nt = 0; nt < 4; nt++) {
                    f32x4 a = zero;
                    a = __builtin_amdgcn_mfma_f32_16x16x32_bf16(qf[s][0], kf[nt][0], a, 0, 0, 0);
                    a = __builtin_amdgcn_mfma_f32_16x16x32_bf16(qf[s][1], kf[nt][1], a, 0, 0, 0);
                    sc[s][nt] = a;
                }
            }
            __builtin_amdgcn_s_setprio(0);

            // phase 2: mask diag, exp2, accumulate l, pack P to LDS
#pragma unroll
            for (int s = 0; s < 2; s++) {
                if (s < s_lo) continue;
                if (kt == ntiles - 2 + s) {
#pragma unroll
                    for (int nt = 0; nt < 4; nt++)
#pragma unroll
                        for (int r = 0; r < 4; r++)
                            sc[s][nt][r] = (nt * 16 + lr <= wid * 16 + quad * 4 + r)
                                               ? sc[s][nt][r] : -INFINITY;
                }
                unsigned short* sPw = sP[wid][s];
#pragma unroll
                for (int nt = 0; nt < 4; nt++)
#pragma unroll
                    for (int r = 0; r < 4; r++) {
                        const float p = fast_exp2(sc[s][nt][r]);
                        l_run[s][r] += p;
                        sPw[(quad * 4 + r) * 72 + nt * 16 + lr] = f32_bf16_rn(p);
                    }
            }

            // V fragments: read ONCE, shared by both strips
            short8 vf[4][2];
#pragma unroll
            for (int nt = 0; nt < 4; nt++) {
                vf[nt][0] = *(const short8*)(bV + (nt * 16 + lr) * 72 + quad * 8);
                vf[nt][1] = *(const short8*)(bV + (nt * 16 + lr) * 72 + 32 + quad * 8);
            }

            // phase 3: P (A-layout) @ V
            __builtin_amdgcn_s_setprio(1);
#pragma unroll
            for (int s = 0; s < 2; s++) {
                if (s < s_lo) continue;
                const unsigned short* sPw = sP[wid][s];
                short8 pa0 = *(const short8*)(sPw + lr * 72 + quad * 8);
                short8 pa1 = *(const short8*)(sPw + lr * 72 + 32 + quad * 8);
#pragma unroll
                for (int nt = 0; nt < 4; nt++) {
                    o[s][nt] = __builtin_amdgcn_mfma_f32_16x16x32_bf16(pa0, vf[nt][0], o[s][nt], 0, 0, 0);
                    o[s][nt] = __builtin_amdgcn_mfma_f32_16x16x32_bf16(pa1, vf[nt][1], o[s][nt], 0, 0, 0);
                }
            }
            __builtin_amdgcn_s_setprio(0);

            __syncthreads();
        }

#pragma unroll
        for (int s = 0; s < 2; s++) {
#pragma unroll
            for (int r = 0; r < 4; r++) {
                float ls = l_run[s][r];
                ls += __shfl_xor(ls, 1);
                ls += __shfl_xor(ls, 2);
                ls += __shfl_xor(ls, 4);
                ls += __shfl_xor(ls, 8);
                const float inv = 1.0f / ls;
                const int t = qb + s * 64 + wid * 16 + quad * 4 + r;
#pragma unroll
                for (int nt = 0; nt < 4; nt++) {
                    const int dim = nt * 16 + lr;
                    y[((size_t)(b * Tt + t)) * Cc + h * HDd + dim] =
                        f32_bf16_rn(o[s][nt][r] * inv);
                }
            }
        }
    }
}

// ---------------- launch ----------------
extern "C" void kernel_launch(void* const* d_in, const int* in_sizes, int n_in,
                              void* d_out, int out_size, void* d_ws, size_t ws_size,
                              hipStream_t stream) {
    const float* x  = (const float*)d_in[0];
    const float* Wk = (const float*)d_in[1];
    const float* bk = (const float*)d_in[2];
    const float* Wq = (const float*)d_in[3];
    const float* bq = (const float*)d_in[4];
    const float* Wv = (const float*)d_in[5];
    const float* bv = (const float*)d_in[6];
    const float* Wp = (const float*)d_in[7];
    const float* bp = (const float*)d_in[8];
    float* out = (float*)d_out;

    char* ws = (char*)d_ws;
    size_t off = 0;
    auto alloc = [&](size_t bytes) { char* p = ws + off; off += bytes; return p; };
    const size_t MK = (size_t)8192 * 1024;
    const size_t NK = (size_t)1024 * 1024;
    unsigned short* xb   = (unsigned short*)alloc(MK * 2);
    unsigned short* Wcat = (unsigned short*)alloc(3 * NK * 2);  // q|k|v contiguous
    unsigned short* Wqb  = Wcat;
    unsigned short* Wkb  = Wcat + NK;
    unsigned short* Wvb  = Wcat + 2 * NK;
    unsigned short* Wpb  = (unsigned short*)alloc(NK * 2);
    unsigned short* qh   = (unsigned short*)alloc(MK * 2);  // [B,H,T,HD], pre-scaled
    unsigned short* kh   = (unsigned short*)alloc(MK * 2);  // [B,H,T,HD]
    unsigned short* vth  = (unsigned short*)alloc(MK * 2);  // [B,H,HD,T]
    unsigned short* ya   = (unsigned short*)alloc(MK * 2);  // [B,T,C]

    // one-time: allow 128 KiB dynamic LDS for the 8-phase GEMM
    // (not a stream op; safe under graph capture, guarded anyway)
    static bool lds_attr_set = false;
    if (!lds_attr_set) {
        (void)hipFuncSetAttribute((const void*)gemm_qkv8,
                                  hipFuncAttributeMaxDynamicSharedMemorySize,
                                  131072);
        lds_attr_set = true;
    }

    cvt_all<<<12288, 256, 0, stream>>>(x, Wq, Wk, Wv, Wp, xb, Wqb, Wkb, Wvb, Wpb);

    gemm_qkv8<<<dim3(12, 32), 512, 131072, stream>>>(xb, Wcat, bq, bk, bv, qh, kh, vth);

    attn<<<dim3(8, 64), 256, 0, stream>>>(qh, kh, vth, ya);

    gemm_proj<<<dim3(16, 64), 256, 0, stream>>>(ya, Wpb, bp, out);
}

// Round 3
// 259.328 us; speedup vs baseline: 1.0770x; 1.0234x over previous
//
#include <hip/hip_runtime.h>
#include <hip/hip_bf16.h>
#include <cmath>

#define Tt 2048
#define Cc 1024
#define Hh 16
#define HDd 64

typedef __attribute__((ext_vector_type(8))) short short8;
typedef __attribute__((ext_vector_type(4))) float f32x4;

// async global->LDS, 16B per lane; lds base must be wave-uniform
#define ASYNC16(gp, lp)                                       \
    __builtin_amdgcn_global_load_lds(                         \
        (const __attribute__((address_space(1))) void*)(gp),  \
        (__attribute__((address_space(3))) void*)(lp), 16, 0, 0)

__device__ __forceinline__ unsigned short f32_bf16(float f) {
    unsigned u = __float_as_uint(f);
    u += 0x7FFF + ((u >> 16) & 1);
    return (unsigned short)(u >> 16);
}
// 2-op round-to-nearest (ties away) — fine for finite values
__device__ __forceinline__ unsigned short f32_bf16_rn(float f) {
    return (unsigned short)((__float_as_uint(f) + 0x8000u) >> 16);
}
__device__ __forceinline__ float fast_exp2(float x) {
#if __has_builtin(__builtin_amdgcn_exp2f)
    return __builtin_amdgcn_exp2f(x);
#else
    return exp2f(x);
#endif
}

// ---------------- fp32 -> bf16 convert: x + all 4 weights, one launch ----
__global__ __launch_bounds__(256) void cvt_all(
    const float* __restrict__ x, const float* __restrict__ a,
    const float* __restrict__ b, const float* __restrict__ c,
    const float* __restrict__ d, unsigned short* __restrict__ ox,
    unsigned short* __restrict__ oa, unsigned short* __restrict__ ob,
    unsigned short* __restrict__ oc, unsigned short* __restrict__ od) {
    const int id = blockIdx.x * 256 + threadIdx.x;
    const float* src; unsigned short* dst; int sub;
    if (id < 2097152) {
        src = x; dst = ox; sub = id;
    } else {
        const int wi = id - 2097152;
        const int which = wi >> 18;
        sub = wi & 262143;
        if (which == 0)      { src = a; dst = oa; }
        else if (which == 1) { src = b; dst = ob; }
        else if (which == 2) { src = c; dst = oc; }
        else                 { src = d; dst = od; }
    }
    float4 v = ((const float4*)src)[sub];
    ushort4 o;
    o.x = f32_bf16(v.x); o.y = f32_bf16(v.y);
    o.z = f32_bf16(v.z); o.w = f32_bf16(v.w);
    ((ushort4*)dst)[sub] = o;
}

// ---------------- fused QKV GEMM: 256x256 8-phase counted-vmcnt ----------
// (unchanged from round 1 — verified)
__global__ __launch_bounds__(512, 2) void gemm_qkv8(
    const unsigned short* __restrict__ A,
    const unsigned short* __restrict__ Wcat,
    const float* __restrict__ bq, const float* __restrict__ bk,
    const float* __restrict__ bv,
    unsigned short* __restrict__ qout, unsigned short* __restrict__ kout,
    unsigned short* __restrict__ vout) {
    extern __shared__ unsigned short lds[];

    const int tid  = threadIdx.x;
    const int wid  = tid >> 6;      // 0..7
    const int lane = tid & 63;
    const int quad = lane >> 4;     // 0..3
    const int lr   = lane & 15;
    const int wr   = wid >> 2;      // 0..1  (M)
    const int wc   = wid & 3;       // 0..3  (N)

    const int bm0 = blockIdx.y * 256;   // grid.y = 32
    const int bn0 = blockIdx.x * 256;   // grid.x = 12

    const int srow  = wid * 8 + (lane >> 3);            // 0..63
    const int scol  = ((lane & 7) ^ (lane >> 3)) * 8;   // swizzled src col
    const int sldso = wid * 512;                        // shorts

    const int a_r   = wr * 64 + lr;
    const int b_r   = wc * 32 + lr;
    const int slot0 = (quad ^ (lr & 7)) * 8;            // ks=0, shorts
    const int slot1 = ((quad ^ 4) ^ (lr & 7)) * 8;      // ks=1

    f32x4 acc[8][4];
    const f32x4 zero = {0.f, 0.f, 0.f, 0.f};
#pragma unroll
    for (int i = 0; i < 8; ++i)
#pragma unroll
        for (int j = 0; j < 4; ++j) acc[i][j] = zero;

    short8 areg[4][2];
    short8 breg[2][2][2];

#define STG(S, BUF, REG, GB, GROW)                                          \
    do {                                                                    \
        if ((S) < 16) {                                                     \
            unsigned short* lb = lds + ((BUF) * 4 + (REG)) * 8192 + sldso;  \
            const unsigned short* gp =                                      \
                (GB) + (size_t)((GROW) + srow) * Cc + (S) * 64 + scol;      \
            ASYNC16(gp, lb);                                                \
            ASYNC16(gp + (size_t)64 * Cc, lb + 4096);                       \
        }                                                                   \
    } while (0)

#define LDA(mh)                                                             \
    do {                                                                    \
        const unsigned short* ab = bufb + (mh) * 8192;                      \
        _Pragma("unroll") for (int mf = 0; mf < 4; ++mf) {                  \
            areg[mf][0] = *(const short8*)(ab + (a_r + mf * 16) * 64 + slot0); \
            areg[mf][1] = *(const short8*)(ab + (a_r + mf * 16) * 64 + slot1); \
        }                                                                   \
    } while (0)

#define LDB(nh)                                                             \
    do {                                                                    \
        const unsigned short* bb = bufb + (2 + (nh)) * 8192;                \
        _Pragma("unroll") for (int nf = 0; nf < 2; ++nf) {                  \
            breg[nh][nf][0] = *(const short8*)(bb + (b_r + nf * 16) * 64 + slot0); \
            breg[nh][nf][1] = *(const short8*)(bb + (b_r + nf * 16) * 64 + slot1); \
        }                                                                   \
    } while (0)

#define MFMA_PHASE(mh, nh)                                                  \
    _Pragma("unroll") for (int mf = 0; mf < 4; ++mf)                        \
    _Pragma("unroll") for (int nf = 0; nf < 2; ++nf) {                      \
        acc[(mh)*4+mf][(nh)*2+nf] = __builtin_amdgcn_mfma_f32_16x16x32_bf16( \
            areg[mf][0], breg[nh][nf][0], acc[(mh)*4+mf][(nh)*2+nf], 0,0,0); \
        acc[(mh)*4+mf][(nh)*2+nf] = __builtin_amdgcn_mfma_f32_16x16x32_bf16( \
            areg[mf][1], breg[nh][nf][1], acc[(mh)*4+mf][(nh)*2+nf], 0,0,0); \
    }

#define TILE(T, BC, WN)                                                     \
    {                                                                       \
        const unsigned short* bufb = lds + (BC) * 32768;                    \
        LDA(0);                                                             \
        LDB(0);                                                             \
        STG((T) + 1, (BC) ^ 1, 1, A, bm0 + 128);                            \
        __builtin_amdgcn_s_barrier();                                       \
        asm volatile("s_waitcnt lgkmcnt(0)" ::: "memory");                  \
        __builtin_amdgcn_s_setprio(1);                                      \
        MFMA_PHASE(0, 0);                                                   \
        __builtin_amdgcn_s_setprio(0);                                      \
        __builtin_amdgcn_s_barrier();                                       \
        LDB(1);                                                             \
        STG((T) + 1, (BC) ^ 1, 3, Wcat, bn0 + 128);                         \
        __builtin_amdgcn_s_barrier();                                       \
        asm volatile("s_waitcnt lgkmcnt(0)" ::: "memory");                  \
        __builtin_amdgcn_s_setprio(1);                                      \
        MFMA_PHASE(0, 1);                                                   \
        __builtin_amdgcn_s_setprio(0);                                      \
        __builtin_amdgcn_s_barrier();                                       \
        LDA(1);                                                             \
        STG((T) + 2, (BC), 0, A, bm0);                                      \
        __builtin_amdgcn_s_barrier();                                       \
        asm volatile("s_waitcnt lgkmcnt(0)" ::: "memory");                  \
        __builtin_amdgcn_s_setprio(1);                                      \
        MFMA_PHASE(1, 0);                                                   \
        __builtin_amdgcn_s_setprio(0);                                      \
        __builtin_amdgcn_s_barrier();                                       \
        STG((T) + 2, (BC), 2, Wcat, bn0);                                   \
        __builtin_amdgcn_s_barrier();                                       \
        __builtin_amdgcn_s_setprio(1);                                      \
        MFMA_PHASE(1, 1);                                                   \
        __builtin_amdgcn_s_setprio(0);                                      \
        asm volatile("s_waitcnt vmcnt(" #WN ")" ::: "memory");              \
        __builtin_amdgcn_s_barrier();                                       \
    }

    STG(0, 0, 0, A, bm0);
    STG(0, 0, 1, A, bm0 + 128);
    STG(0, 0, 2, Wcat, bn0);
    STG(0, 0, 3, Wcat, bn0 + 128);
    STG(1, 1, 0, A, bm0);
    STG(1, 1, 2, Wcat, bn0);
    asm volatile("s_waitcnt vmcnt(4)" ::: "memory");
    __builtin_amdgcn_s_barrier();

    for (int t2 = 0; t2 < 7; ++t2) {
        const int T0 = t2 * 2;
        TILE(T0, 0, 4);
        TILE(T0 + 1, 1, 4);
    }
    TILE(14, 0, 0);
    TILE(15, 1, 0);

#undef TILE
#undef MFMA_PHASE
#undef LDB
#undef LDA
#undef STG

    const int which = bn0 >> 10;  // 0=q 1=k 2=v
    const float* bias = (which == 0) ? bq : (which == 1) ? bk : bv;
    unsigned short* outp = (which == 0) ? qout : (which == 1) ? kout : vout;
    const float scale = (which == 0) ? 0.1803368801111204f : 1.0f;  // 0.125*log2e
    const bool vmode = (which == 2);
    const int nb = bn0 & 1023;

#pragma unroll
    for (int nh = 0; nh < 2; ++nh)
#pragma unroll
        for (int nf = 0; nf < 2; ++nf) {
            const int nl = nb + nh * 128 + wc * 32 + nf * 16 + lr;
            const float bvv = bias[nl];
            const int h = nl >> 6, hd = nl & 63;
#pragma unroll
            for (int mh = 0; mh < 2; ++mh)
#pragma unroll
                for (int mf = 0; mf < 4; ++mf) {
                    const f32x4 a = acc[mh * 4 + mf][nh * 2 + nf];
                    const int m0 = bm0 + mh * 128 + wr * 64 + mf * 16 + quad * 4;
                    const int b = m0 >> 11, t0 = m0 & 2047;
                    if (vmode) {
                        ushort4 pk;
                        pk.x = f32_bf16_rn(a[0] + bvv);
                        pk.y = f32_bf16_rn(a[1] + bvv);
                        pk.z = f32_bf16_rn(a[2] + bvv);
                        pk.w = f32_bf16_rn(a[3] + bvv);
                        *(ushort4*)(outp + (((size_t)(b * Hh + h)) * HDd + hd) * Tt + t0) = pk;
                    } else {
#pragma unroll
                        for (int r = 0; r < 4; ++r) {
                            outp[(((size_t)(b * Hh + h)) * Tt + t0 + r) * HDd + hd] =
                                f32_bf16_rn((a[r] + bvv) * scale);
                        }
                    }
                }
        }
}

// ---------------- output projection GEMM: 128x64 tiles, fp32 out ---------
__global__ __launch_bounds__(256) void gemm_proj(const unsigned short* __restrict__ A,
                                                 const unsigned short* __restrict__ W,
                                                 const float* __restrict__ bias,
                                                 float* __restrict__ out) {
    __shared__ unsigned short sA[2][128 * 32];
    __shared__ unsigned short sB[2][64 * 32];

    const int tid  = threadIdx.x;
    const int bm0  = blockIdx.y * 128;
    const int bn0  = blockIdx.x * 64;
    const int wid  = tid >> 6;
    const int lane = tid & 63;
    const int quad = lane >> 4;
    const int lr   = lane & 15;
    const int wm   = (wid & 1) * 64;
    const int wn   = (wid >> 1) * 32;

    const int sr   = lane >> 2;
    const int scol = (lane & 3) * 8;
    const int row0 = wid * 16 + sr;
    const int row1 = 64 + wid * 16 + sr;
    const int lo0  = wid * 512;
    const int lo1  = (4 + wid) * 512;

    f32x4 acc[4][2];
    f32x4 zero = {0.f, 0.f, 0.f, 0.f};
#pragma unroll
    for (int i = 0; i < 4; i++)
#pragma unroll
        for (int j = 0; j < 2; j++) acc[i][j] = zero;

    ASYNC16(A + (size_t)(bm0 + row0) * Cc + scol, sA[0] + lo0);
    ASYNC16(A + (size_t)(bm0 + row1) * Cc + scol, sA[0] + lo1);
    ASYNC16(W + (size_t)(bn0 + row0) * Cc + scol, sB[0] + lo0);
    __syncthreads();

    for (int kt = 0; kt < Cc / 32; ++kt) {
        const int cur = kt & 1, nxt = cur ^ 1;
        if (kt + 1 < Cc / 32) {
            const int kb = (kt + 1) * 32;
            ASYNC16(A + (size_t)(bm0 + row0) * Cc + kb + scol, sA[nxt] + lo0);
            ASYNC16(A + (size_t)(bm0 + row1) * Cc + kb + scol, sA[nxt] + lo1);
            ASYNC16(W + (size_t)(bn0 + row0) * Cc + kb + scol, sB[nxt] + lo0);
        }

        short8 af[4], bf[2];
#pragma unroll
        for (int i = 0; i < 4; i++)
            af[i] = *(const short8*)(sA[cur] + (wm + i * 16 + lr) * 32 + quad * 8);
#pragma unroll
        for (int j = 0; j < 2; j++)
            bf[j] = *(const short8*)(sB[cur] + (wn + j * 16 + lr) * 32 + quad * 8);
#pragma unroll
        for (int i = 0; i < 4; i++)
#pragma unroll
            for (int j = 0; j < 2; j++)
                acc[i][j] = __builtin_amdgcn_mfma_f32_16x16x32_bf16(af[i], bf[j], acc[i][j], 0, 0, 0);

        __syncthreads();
    }

#pragma unroll
    for (int j = 0; j < 2; j++) {
        const int n = bn0 + wn + j * 16 + lr;
        const float bvv = bias[n];
#pragma unroll
        for (int i = 0; i < 4; i++)
#pragma unroll
            for (int r = 0; r < 4; r++) {
                const int m = bm0 + wm + i * 16 + quad * 4 + r;
                out[(size_t)m * Cc + n] = acc[i][j][r] + bvv;
            }
    }
}

// ---------------- flash attention: 64-row Q-tiles, 4 blocks/CU -----------
// grid (64, 16): head = blockIdx.x (XCD = head&7 -> all 16 q-blocks of a
// head share one XCD, 8 heads/XCD = 4 MB K/V = L2). qx = blockIdx.y.
// Block = 4 waves x ONE 16-row strip = 64 Q rows. Pass pair (qx, 31-qx)
// -> exactly 33 k-tile iters per block; 1024 balanced blocks = 4/CU =
// 16 waves/CU = 4 waves/SIMD (2x round-1: kernel was issue/latency-bound
// at 2 waves/SIMD, VALUBusy 43%, MfmaUtil 18%).
// LDS 40960 B: K/V 64x64 double-buffered, XOR-swizzled (slot ^= row&7) —
// staged via global_load_lds with pre-swizzled SOURCE + swizzled reads
// (both-sides-or-neither). Per-wave sP [16][64] swizzled. One
// __syncthreads per iter (drains vmcnt for the async stage issued at the
// iter top). Unnormalized log2-domain softmax (q pre-scaled by 0.125*log2e).
__global__ __launch_bounds__(256, 4) void attn(const unsigned short* __restrict__ q,
                                               const unsigned short* __restrict__ k,
                                               const unsigned short* __restrict__ vt,
                                               unsigned short* __restrict__ y) {
    __shared__ unsigned short sK[2][64 * 64];
    __shared__ unsigned short sV[2][64 * 64];
    __shared__ unsigned short sP[4][16 * 64];

    const int tid  = threadIdx.x;
    const int wid  = tid >> 6;
    const int lane = tid & 63;
    const int quad = lane >> 4;
    const int lr   = lane & 15;

    const int bh = blockIdx.x;            // head
    const int qx = blockIdx.y;            // 0..15
    const size_t headq = (size_t)bh * Tt * HDd;
    const unsigned short* kg = k + headq;
    const unsigned short* vg = vt + headq;
    const int b = bh >> 4, h = bh & 15;

    // staging: each wave stages 16 K rows + 16 V rows per tile (2+2 calls)
    const int g_r = lane >> 3;                       // 0..7
    const int g_c = ((lane & 7) ^ g_r) * 8;          // pre-swizzled src col
    const unsigned short* kst = kg + (size_t)(wid * 16 + g_r) * HDd + g_c;
    const unsigned short* vst = vg + (size_t)(wid * 16 + g_r) * Tt + g_c;
    unsigned short* dK0 = sK[0] + wid * 1024;
    unsigned short* dK1 = sK[1] + wid * 1024;
    unsigned short* dV0 = sV[0] + wid * 1024;
    unsigned short* dV1 = sV[1] + wid * 1024;

#define STAGE_KV(BUF, KB)                                                   \
    do {                                                                    \
        unsigned short* dK = (BUF) ? dK1 : dK0;                             \
        unsigned short* dV = (BUF) ? dV1 : dV0;                             \
        ASYNC16(kst + (size_t)(KB) * HDd,       dK);                        \
        ASYNC16(kst + (size_t)((KB) + 8) * HDd, dK + 512);                  \
        ASYNC16(vst + (KB),                     dV);                        \
        ASYNC16(vst + (size_t)8 * Tt + (KB),    dV + 512);                  \
    } while (0)

    // fragment read base: row lr, logical slot (ks*4+quad), phys ^= (lr&7)
    const int fr_off = lr * 64 + ((quad ^ (lr & 7)) * 8);   // shorts; ks1: ^32
    // P write: row=quad*4+r, phys slot = (nt*2|hi) ^ ((quad&1)*4|r)
    const int hq8 = (((lr >> 3) ^ ((quad & 1) << 2)) * 8);
    const int pwb = quad * 256 + (lr & 7);
    unsigned short* sPw = sP[wid];

    const f32x4 zero = {0.f, 0.f, 0.f, 0.f};

    for (int pass = 0; pass < 2; ++pass) {
        const int qt = pass ? (31 - qx) : qx;
        const int qb = qt * 64;
        const int ntiles = qt + 1;

        const unsigned short* qp = q + headq + (size_t)(qb + wid * 16 + lr) * HDd;
        const short8 qf0 = *(const short8*)(qp + quad * 8);
        const short8 qf1 = *(const short8*)(qp + 32 + quad * 8);

        f32x4 o[4];
        float l_run[4];
#pragma unroll
        for (int i = 0; i < 4; i++) { o[i] = zero; l_run[i] = 0.f; }

        STAGE_KV(0, 0);
        __syncthreads();

        for (int kt = 0; kt < ntiles; ++kt) {
            const int cur = kt & 1;
            if (kt + 1 < ntiles) STAGE_KV(cur ^ 1, (kt + 1) * 64);

            const unsigned short* bK = sK[cur];
            const unsigned short* bV = sV[cur];

            // K fragments (swizzled reads)
            short8 kf[4][2];
#pragma unroll
            for (int nt = 0; nt < 4; nt++) {
                kf[nt][0] = *(const short8*)(bK + nt * 1024 + fr_off);
                kf[nt][1] = *(const short8*)(bK + nt * 1024 + (fr_off ^ 32));
            }

            // QK^T
            f32x4 sc[4];
            __builtin_amdgcn_s_setprio(1);
#pragma unroll
            for (int nt = 0; nt < 4; nt++) {
                f32x4 a = __builtin_amdgcn_mfma_f32_16x16x32_bf16(qf0, kf[nt][0], zero, 0, 0, 0);
                sc[nt]  = __builtin_amdgcn_mfma_f32_16x16x32_bf16(qf1, kf[nt][1], a, 0, 0, 0);
            }
            __builtin_amdgcn_s_setprio(0);

            // V fragments (shared by PV below)
            short8 vf[4][2];
#pragma unroll
            for (int nt = 0; nt < 4; nt++) {
                vf[nt][0] = *(const short8*)(bV + nt * 1024 + fr_off);
                vf[nt][1] = *(const short8*)(bV + nt * 1024 + (fr_off ^ 32));
            }

            // diagonal mask (uniform branch; only on the last tile)
            if (kt == qt) {
#pragma unroll
                for (int nt = 0; nt < 4; nt++)
#pragma unroll
                    for (int r = 0; r < 4; r++)
                        sc[nt][r] = (nt * 16 + lr <= wid * 16 + quad * 4 + r)
                                        ? sc[nt][r] : -INFINITY;
            }

            // exp2, l accumulation, pack P to swizzled LDS
#pragma unroll
            for (int nt = 0; nt < 4; nt++)
#pragma unroll
                for (int r = 0; r < 4; r++) {
                    const float p = fast_exp2(sc[nt][r]);
                    l_run[r] += p;
                    sPw[pwb + r * 64 + ((nt * 16 ^ r * 8) ^ hq8)] = f32_bf16_rn(p);
                }

            // P as A-fragment (swizzled read, row = lr)
            const short8 pa0 = *(const short8*)(sPw + fr_off);
            const short8 pa1 = *(const short8*)(sPw + (fr_off ^ 32));

            // PV
            __builtin_amdgcn_s_setprio(1);
#pragma unroll
            for (int nt = 0; nt < 4; nt++) {
                o[nt] = __builtin_amdgcn_mfma_f32_16x16x32_bf16(pa0, vf[nt][0], o[nt], 0, 0, 0);
                o[nt] = __builtin_amdgcn_mfma_f32_16x16x32_bf16(pa1, vf[nt][1], o[nt], 0, 0, 0);
            }
            __builtin_amdgcn_s_setprio(0);

            __syncthreads();
        }

        // normalize + write
#pragma unroll
        for (int r = 0; r < 4; r++) {
            float ls = l_run[r];
            ls += __shfl_xor(ls, 1);
            ls += __shfl_xor(ls, 2);
            ls += __shfl_xor(ls, 4);
            ls += __shfl_xor(ls, 8);
            const float inv = 1.0f / ls;
            const int t = qb + wid * 16 + quad * 4 + r;
#pragma unroll
            for (int nt = 0; nt < 4; nt++) {
                const int dim = nt * 16 + lr;
                y[((size_t)(b * Tt + t)) * Cc + h * HDd + dim] =
                    f32_bf16_rn(o[nt][r] * inv);
            }
        }
    }
#undef STAGE_KV
}

// ---------------- launch ----------------
extern "C" void kernel_launch(void* const* d_in, const int* in_sizes, int n_in,
                              void* d_out, int out_size, void* d_ws, size_t ws_size,
                              hipStream_t stream) {
    const float* x  = (const float*)d_in[0];
    const float* Wk = (const float*)d_in[1];
    const float* bk = (const float*)d_in[2];
    const float* Wq = (const float*)d_in[3];
    const float* bq = (const float*)d_in[4];
    const float* Wv = (const float*)d_in[5];
    const float* bv = (const float*)d_in[6];
    const float* Wp = (const float*)d_in[7];
    const float* bp = (const float*)d_in[8];
    float* out = (float*)d_out;

    char* ws = (char*)d_ws;
    size_t off = 0;
    auto alloc = [&](size_t bytes) { char* p = ws + off; off += bytes; return p; };
    const size_t MK = (size_t)8192 * 1024;
    const size_t NK = (size_t)1024 * 1024;
    unsigned short* xb   = (unsigned short*)alloc(MK * 2);
    unsigned short* Wcat = (unsigned short*)alloc(3 * NK * 2);  // q|k|v contiguous
    unsigned short* Wqb  = Wcat;
    unsigned short* Wkb  = Wcat + NK;
    unsigned short* Wvb  = Wcat + 2 * NK;
    unsigned short* Wpb  = (unsigned short*)alloc(NK * 2);
    unsigned short* qh   = (unsigned short*)alloc(MK * 2);  // [B,H,T,HD], pre-scaled
    unsigned short* kh   = (unsigned short*)alloc(MK * 2);  // [B,H,T,HD]
    unsigned short* vth  = (unsigned short*)alloc(MK * 2);  // [B,H,HD,T]
    unsigned short* ya   = (unsigned short*)alloc(MK * 2);  // [B,T,C]

    static bool lds_attr_set = false;
    if (!lds_attr_set) {
        (void)hipFuncSetAttribute((const void*)gemm_qkv8,
                                  hipFuncAttributeMaxDynamicSharedMemorySize,
                                  131072);
        lds_attr_set = true;
    }

    cvt_all<<<12288, 256, 0, stream>>>(x, Wq, Wk, Wv, Wp, xb, Wqb, Wkb, Wvb, Wpb);

    gemm_qkv8<<<dim3(12, 32), 512, 131072, stream>>>(xb, Wcat, bq, bk, bv, qh, kh, vth);

    attn<<<dim3(64, 16), 256, 0, stream>>>(qh, kh, vth, ya);

    gemm_proj<<<dim3(16, 64), 256, 0, stream>>>(ya, Wpb, bp, out);
}

// Round 4
// 246.999 us; speedup vs baseline: 1.1307x; 1.0499x over previous
//
#include <hip/hip_runtime.h>
#include <hip/hip_bf16.h>
#include <cmath>

#define Tt 2048
#define Cc 1024
#define Hh 16
#define HDd 64

typedef __attribute__((ext_vector_type(8))) short short8;
typedef __attribute__((ext_vector_type(4))) float f32x4;

// async global->LDS, 16B per lane; lds base must be wave-uniform
#define ASYNC16(gp, lp)                                       \
    __builtin_amdgcn_global_load_lds(                         \
        (const __attribute__((address_space(1))) void*)(gp),  \
        (__attribute__((address_space(3))) void*)(lp), 16, 0, 0)

__device__ __forceinline__ unsigned short f32_bf16(float f) {
    unsigned u = __float_as_uint(f);
    u += 0x7FFF + ((u >> 16) & 1);
    return (unsigned short)(u >> 16);
}
// 2-op round-to-nearest (ties away) — fine for finite values
__device__ __forceinline__ unsigned short f32_bf16_rn(float f) {
    return (unsigned short)((__float_as_uint(f) + 0x8000u) >> 16);
}
__device__ __forceinline__ float fast_exp2(float x) {
#if __has_builtin(__builtin_amdgcn_exp2f)
    return __builtin_amdgcn_exp2f(x);
#else
    return exp2f(x);
#endif
}

// ---------------- fp32 -> bf16 convert: x + all 4 weights, one launch ----
__global__ __launch_bounds__(256) void cvt_all(
    const float* __restrict__ x, const float* __restrict__ a,
    const float* __restrict__ b, const float* __restrict__ c,
    const float* __restrict__ d, unsigned short* __restrict__ ox,
    unsigned short* __restrict__ oa, unsigned short* __restrict__ ob,
    unsigned short* __restrict__ oc, unsigned short* __restrict__ od) {
    const int id = blockIdx.x * 256 + threadIdx.x;
    const float* src; unsigned short* dst; int sub;
    if (id < 2097152) {
        src = x; dst = ox; sub = id;
    } else {
        const int wi = id - 2097152;
        const int which = wi >> 18;
        sub = wi & 262143;
        if (which == 0)      { src = a; dst = oa; }
        else if (which == 1) { src = b; dst = ob; }
        else if (which == 2) { src = c; dst = oc; }
        else                 { src = d; dst = od; }
    }
    float4 v = ((const float4*)src)[sub];
    ushort4 o;
    o.x = f32_bf16(v.x); o.y = f32_bf16(v.y);
    o.z = f32_bf16(v.z); o.w = f32_bf16(v.w);
    ((ushort4*)dst)[sub] = o;
}

// ---------------- fused QKV GEMM: 256x256 8-phase counted-vmcnt ----------
// Round-3 change: SLAB-SWIZZLED block mapping. Staging traffic is
// 384 tiles x 64KB/K-tile x 16 = 393 MB; with linear ids the panel
// sharers (12 for A, 32 for B) land on different XCDs -> traffic served
// by L3 (~12 TB/s) = ~33 us floor (the measured 5527 cyc/K-tile).
// Slab map: XCD = id%8 owns 4x4 tile slabs -> A/B panel sharers
// co-resident per XCD; sliding K-window ~512 KB << 4 MB L2 -> staging
// served by L2 (34.5 TB/s). Everything else unchanged (verified).
__global__ __launch_bounds__(512, 2) void gemm_qkv8(
    const unsigned short* __restrict__ A,
    const unsigned short* __restrict__ Wcat,
    const float* __restrict__ bq, const float* __restrict__ bk,
    const float* __restrict__ bv,
    unsigned short* __restrict__ qout, unsigned short* __restrict__ kout,
    unsigned short* __restrict__ vout) {
    extern __shared__ unsigned short lds[];

    const int tid  = threadIdx.x;
    const int wid  = tid >> 6;      // 0..7
    const int lane = tid & 63;
    const int quad = lane >> 4;     // 0..3
    const int lr   = lane & 15;
    const int wr   = wid >> 2;      // 0..1  (M)
    const int wc   = wid & 3;       // 0..3  (N)

    // slab swizzle: 384 blocks = 8 XCD x 3 slabs x 16; slab = 4y x 4x tiles
    const int id   = blockIdx.y * 12 + blockIdx.x;  // == linear dispatch id
    const int xcd  = id & 7;
    const int rank = id >> 3;        // 0..47
    const int ls   = rank >> 4;      // 0..2
    const int w    = rank & 15;      // 0..15
    const int sID  = ls * 8 + xcd;   // 0..23
    const int by   = (sID / 3) * 4 + (w >> 2);   // 0..31
    const int bx   = (sID % 3) * 4 + (w & 3);    // 0..11
    const int bm0  = by * 256;
    const int bn0  = bx * 256;

    const int srow  = wid * 8 + (lane >> 3);            // 0..63
    const int scol  = ((lane & 7) ^ (lane >> 3)) * 8;   // swizzled src col
    const int sldso = wid * 512;                        // shorts

    const int a_r   = wr * 64 + lr;
    const int b_r   = wc * 32 + lr;
    const int slot0 = (quad ^ (lr & 7)) * 8;            // ks=0, shorts
    const int slot1 = ((quad ^ 4) ^ (lr & 7)) * 8;      // ks=1

    f32x4 acc[8][4];
    const f32x4 zero = {0.f, 0.f, 0.f, 0.f};
#pragma unroll
    for (int i = 0; i < 8; ++i)
#pragma unroll
        for (int j = 0; j < 4; ++j) acc[i][j] = zero;

    short8 areg[4][2];
    short8 breg[2][2][2];

#define STG(S, BUF, REG, GB, GROW)                                          \
    do {                                                                    \
        if ((S) < 16) {                                                     \
            unsigned short* lb = lds + ((BUF) * 4 + (REG)) * 8192 + sldso;  \
            const unsigned short* gp =                                      \
                (GB) + (size_t)((GROW) + srow) * Cc + (S) * 64 + scol;      \
            ASYNC16(gp, lb);                                                \
            ASYNC16(gp + (size_t)64 * Cc, lb + 4096);                       \
        }                                                                   \
    } while (0)

#define LDA(mh)                                                             \
    do {                                                                    \
        const unsigned short* ab = bufb + (mh) * 8192;                      \
        _Pragma("unroll") for (int mf = 0; mf < 4; ++mf) {                  \
            areg[mf][0] = *(const short8*)(ab + (a_r + mf * 16) * 64 + slot0); \
            areg[mf][1] = *(const short8*)(ab + (a_r + mf * 16) * 64 + slot1); \
        }                                                                   \
    } while (0)

#define LDB(nh)                                                             \
    do {                                                                    \
        const unsigned short* bb = bufb + (2 + (nh)) * 8192;                \
        _Pragma("unroll") for (int nf = 0; nf < 2; ++nf) {                  \
            breg[nh][nf][0] = *(const short8*)(bb + (b_r + nf * 16) * 64 + slot0); \
            breg[nh][nf][1] = *(const short8*)(bb + (b_r + nf * 16) * 64 + slot1); \
        }                                                                   \
    } while (0)

#define MFMA_PHASE(mh, nh)                                                  \
    _Pragma("unroll") for (int mf = 0; mf < 4; ++mf)                        \
    _Pragma("unroll") for (int nf = 0; nf < 2; ++nf) {                      \
        acc[(mh)*4+mf][(nh)*2+nf] = __builtin_amdgcn_mfma_f32_16x16x32_bf16( \
            areg[mf][0], breg[nh][nf][0], acc[(mh)*4+mf][(nh)*2+nf], 0,0,0); \
        acc[(mh)*4+mf][(nh)*2+nf] = __builtin_amdgcn_mfma_f32_16x16x32_bf16( \
            areg[mf][1], breg[nh][nf][1], acc[(mh)*4+mf][(nh)*2+nf], 0,0,0); \
    }

#define TILE(T, BC, WN)                                                     \
    {                                                                       \
        const unsigned short* bufb = lds + (BC) * 32768;                    \
        LDA(0);                                                             \
        LDB(0);                                                             \
        STG((T) + 1, (BC) ^ 1, 1, A, bm0 + 128);                            \
        __builtin_amdgcn_s_barrier();                                       \
        asm volatile("s_waitcnt lgkmcnt(0)" ::: "memory");                  \
        __builtin_amdgcn_s_setprio(1);                                      \
        MFMA_PHASE(0, 0);                                                   \
        __builtin_amdgcn_s_setprio(0);                                      \
        __builtin_amdgcn_s_barrier();                                       \
        LDB(1);                                                             \
        STG((T) + 1, (BC) ^ 1, 3, Wcat, bn0 + 128);                         \
        __builtin_amdgcn_s_barrier();                                       \
        asm volatile("s_waitcnt lgkmcnt(0)" ::: "memory");                  \
        __builtin_amdgcn_s_setprio(1);                                      \
        MFMA_PHASE(0, 1);                                                   \
        __builtin_amdgcn_s_setprio(0);                                      \
        __builtin_amdgcn_s_barrier();                                       \
        LDA(1);                                                             \
        STG((T) + 2, (BC), 0, A, bm0);                                      \
        __builtin_amdgcn_s_barrier();                                       \
        asm volatile("s_waitcnt lgkmcnt(0)" ::: "memory");                  \
        __builtin_amdgcn_s_setprio(1);                                      \
        MFMA_PHASE(1, 0);                                                   \
        __builtin_amdgcn_s_setprio(0);                                      \
        __builtin_amdgcn_s_barrier();                                       \
        STG((T) + 2, (BC), 2, Wcat, bn0);                                   \
        __builtin_amdgcn_s_barrier();                                       \
        __builtin_amdgcn_s_setprio(1);                                      \
        MFMA_PHASE(1, 1);                                                   \
        __builtin_amdgcn_s_setprio(0);                                      \
        asm volatile("s_waitcnt vmcnt(" #WN ")" ::: "memory");              \
        __builtin_amdgcn_s_barrier();                                       \
    }

    STG(0, 0, 0, A, bm0);
    STG(0, 0, 1, A, bm0 + 128);
    STG(0, 0, 2, Wcat, bn0);
    STG(0, 0, 3, Wcat, bn0 + 128);
    STG(1, 1, 0, A, bm0);
    STG(1, 1, 2, Wcat, bn0);
    asm volatile("s_waitcnt vmcnt(4)" ::: "memory");
    __builtin_amdgcn_s_barrier();

    for (int t2 = 0; t2 < 7; ++t2) {
        const int T0 = t2 * 2;
        TILE(T0, 0, 4);
        TILE(T0 + 1, 1, 4);
    }
    TILE(14, 0, 0);
    TILE(15, 1, 0);

#undef TILE
#undef MFMA_PHASE
#undef LDB
#undef LDA
#undef STG

    const int which = bn0 >> 10;  // 0=q 1=k 2=v
    const float* bias = (which == 0) ? bq : (which == 1) ? bk : bv;
    unsigned short* outp = (which == 0) ? qout : (which == 1) ? kout : vout;
    const float scale = (which == 0) ? 0.1803368801111204f : 1.0f;  // 0.125*log2e
    const bool vmode = (which == 2);
    const int nb = bn0 & 1023;

#pragma unroll
    for (int nh = 0; nh < 2; ++nh)
#pragma unroll
        for (int nf = 0; nf < 2; ++nf) {
            const int nl = nb + nh * 128 + wc * 32 + nf * 16 + lr;
            const float bvv = bias[nl];
            const int h = nl >> 6, hd = nl & 63;
#pragma unroll
            for (int mh = 0; mh < 2; ++mh)
#pragma unroll
                for (int mf = 0; mf < 4; ++mf) {
                    const f32x4 a = acc[mh * 4 + mf][nh * 2 + nf];
                    const int m0 = bm0 + mh * 128 + wr * 64 + mf * 16 + quad * 4;
                    const int b = m0 >> 11, t0 = m0 & 2047;
                    if (vmode) {
                        ushort4 pk;
                        pk.x = f32_bf16_rn(a[0] + bvv);
                        pk.y = f32_bf16_rn(a[1] + bvv);
                        pk.z = f32_bf16_rn(a[2] + bvv);
                        pk.w = f32_bf16_rn(a[3] + bvv);
                        *(ushort4*)(outp + (((size_t)(b * Hh + h)) * HDd + hd) * Tt + t0) = pk;
                    } else {
#pragma unroll
                        for (int r = 0; r < 4; ++r) {
                            outp[(((size_t)(b * Hh + h)) * Tt + t0 + r) * HDd + hd] =
                                f32_bf16_rn((a[r] + bvv) * scale);
                        }
                    }
                }
        }
}

// ---------------- output projection GEMM: 256x128 2-phase template -------
// Clone of gemm_qkv8's verified structure with BN=128 and 2 fat phases per
// K-tile. Grid (8,32) = 256 blocks = EXACTLY one residency generation
// (old 128x64 tiling staged 402 MB over 1024 blocks -> L3-BW-bound).
// Staged bytes now 196 MB; slab map: XCD = id%8 owns 4 y-rows x all 8 x
// -> per-XCD panel set = 4x512KB(A) + 8x256KB(B) = 4 MB = L2.
// LDS: 2 buf x [A-h0 8192 | A-h1 8192 | B-h0 4096 | B-h1 4096] shorts
//    = 98304 B (1 block/CU). Counted vmcnt(3): T+2's 3 calls stay in
// flight across each tile boundary.
__global__ __launch_bounds__(512, 2) void gemm_proj8(
    const unsigned short* __restrict__ A,
    const unsigned short* __restrict__ W,
    const float* __restrict__ bias,
    float* __restrict__ out) {
    extern __shared__ unsigned short lds[];

    const int tid  = threadIdx.x;
    const int wid  = tid >> 6;
    const int lane = tid & 63;
    const int quad = lane >> 4;
    const int lr   = lane & 15;
    const int wr   = wid >> 2;      // 0..1
    const int wc   = wid & 3;       // 0..3

    // slab swizzle: id = x + 8y; xcd = x; each XCD: y-slab of 4, all x
    const int id   = blockIdx.y * 8 + blockIdx.x;
    const int xcd  = id & 7;
    const int rank = id >> 3;          // 0..31
    const int by   = xcd * 4 + (rank >> 3);  // 0..31
    const int bx   = rank & 7;               // 0..7
    const int bm0  = by * 256;
    const int bn0  = bx * 128;

    const int srow  = wid * 8 + (lane >> 3);
    const int scol  = ((lane & 7) ^ (lane >> 3)) * 8;
    const int sldso = wid * 512;

    const int a_r   = wr * 64 + lr;
    const int b_r2  = (wc & 1) * 32 + lr;     // row within own B region
    const int breg_off = 16384 + (wc >> 1) * 4096;  // wave's B region
    const int slot0 = (quad ^ (lr & 7)) * 8;
    const int slot1 = ((quad ^ 4) ^ (lr & 7)) * 8;

    f32x4 acc[8][2];
    const f32x4 zero = {0.f, 0.f, 0.f, 0.f};
#pragma unroll
    for (int i = 0; i < 8; ++i)
#pragma unroll
        for (int j = 0; j < 2; ++j) acc[i][j] = zero;

    short8 areg[4][2];
    short8 breg[2][2];

// A half-tile (128 rows) = 2 calls; REG_OFF in {0, 8192}
#define STGA(S, BUF, REG_OFF, GROW)                                         \
    do {                                                                    \
        if ((S) < 16) {                                                     \
            unsigned short* lb = lds + (BUF) * 24576 + (REG_OFF) + sldso;   \
            const unsigned short* gp =                                      \
                A + (size_t)(bm0 + (GROW) + srow) * Cc + (S) * 64 + scol;   \
            ASYNC16(gp, lb);                                                \
            ASYNC16(gp + (size_t)64 * Cc, lb + 4096);                       \
        }                                                                   \
    } while (0)

// B half-tile (64 rows) = 1 call; REG_OFF in {16384, 20480}, NROW 0/64
#define STGB(S, BUF, REG_OFF, NROW)                                         \
    do {                                                                    \
        if ((S) < 16) {                                                     \
            unsigned short* lb = lds + (BUF) * 24576 + (REG_OFF) + sldso;   \
            const unsigned short* gp =                                      \
                W + (size_t)(bn0 + (NROW) + srow) * Cc + (S) * 64 + scol;   \
            ASYNC16(gp, lb);                                                \
        }                                                                   \
    } while (0)

#define LDA_P(mh)                                                           \
    do {                                                                    \
        const unsigned short* ab = bufb + (mh) * 8192;                      \
        _Pragma("unroll") for (int mf = 0; mf < 4; ++mf) {                  \
            areg[mf][0] = *(const short8*)(ab + (a_r + mf * 16) * 64 + slot0); \
            areg[mf][1] = *(const short8*)(ab + (a_r + mf * 16) * 64 + slot1); \
        }                                                                   \
    } while (0)

#define LDB_P                                                               \
    do {                                                                    \
        const unsigned short* bb = bufb + breg_off;                         \
        _Pragma("unroll") for (int nf = 0; nf < 2; ++nf) {                  \
            breg[nf][0] = *(const short8*)(bb + (b_r2 + nf * 16) * 64 + slot0); \
            breg[nf][1] = *(const short8*)(bb + (b_r2 + nf * 16) * 64 + slot1); \
        }                                                                   \
    } while (0)

#define MFMA_P(mh)                                                          \
    _Pragma("unroll") for (int mf = 0; mf < 4; ++mf)                        \
    _Pragma("unroll") for (int nf = 0; nf < 2; ++nf) {                      \
        acc[(mh)*4+mf][nf] = __builtin_amdgcn_mfma_f32_16x16x32_bf16(       \
            areg[mf][0], breg[nf][0], acc[(mh)*4+mf][nf], 0, 0, 0);         \
        acc[(mh)*4+mf][nf] = __builtin_amdgcn_mfma_f32_16x16x32_bf16(       \
            areg[mf][1], breg[nf][1], acc[(mh)*4+mf][nf], 0, 0, 0);         \
    }

// 2 phases: p1 {LDA(0)+LDB, stage T+1 A-h1/B-h1 -> buf^1, MFMA mh0},
//           p2 {LDA(1), stage T+2 A-h0/B-h0 -> buf (A-h0/B-h0 last read
//               at p1, >=1 barrier earlier), MFMA mh1, vmcnt(WN)}.
// Steady outstanding at boundary = T+2's 3 calls -> WN=3.
#define TILE_P(T, BC, WN)                                                   \
    {                                                                       \
        const unsigned short* bufb = lds + (BC) * 24576;                    \
        LDA_P(0);                                                           \
        LDB_P;                                                              \
        STGA((T) + 1, (BC) ^ 1, 8192, 128);                                 \
        STGB((T) + 1, (BC) ^ 1, 20480, 64);                                 \
        __builtin_amdgcn_s_barrier();                                       \
        asm volatile("s_waitcnt lgkmcnt(0)" ::: "memory");                  \
        __builtin_amdgcn_s_setprio(1);                                      \
        MFMA_P(0);                                                          \
        __builtin_amdgcn_s_setprio(0);                                      \
        __builtin_amdgcn_s_barrier();                                       \
        LDA_P(1);                                                           \
        STGA((T) + 2, (BC), 0, 0);                                          \
        STGB((T) + 2, (BC), 16384, 0);                                      \
        __builtin_amdgcn_s_barrier();                                       \
        asm volatile("s_waitcnt lgkmcnt(0)" ::: "memory");                  \
        __builtin_amdgcn_s_setprio(1);                                      \
        MFMA_P(1);                                                          \
        __builtin_amdgcn_s_setprio(0);                                      \
        asm volatile("s_waitcnt vmcnt(" #WN ")" ::: "memory");              \
        __builtin_amdgcn_s_barrier();                                       \
    }

    // prologue: T0 complete (6 calls) + T1 {A-h0, B-h0} (3 calls)
    STGA(0, 0, 0, 0);
    STGA(0, 0, 8192, 128);
    STGB(0, 0, 16384, 0);
    STGB(0, 0, 20480, 64);
    STGA(1, 1, 0, 0);
    STGB(1, 1, 16384, 0);
    asm volatile("s_waitcnt vmcnt(3)" ::: "memory");
    __builtin_amdgcn_s_barrier();

    for (int t2 = 0; t2 < 7; ++t2) {
        const int T0 = t2 * 2;
        TILE_P(T0, 0, 3);
        TILE_P(T0 + 1, 1, 3);
    }
    TILE_P(14, 0, 0);
    TILE_P(15, 1, 0);

#undef TILE_P
#undef MFMA_P
#undef LDB_P
#undef LDA_P
#undef STGB
#undef STGA

    // epilogue: fp32 out + bias; 16-lane-consecutive n -> 64B chunks
#pragma unroll
    for (int nf = 0; nf < 2; ++nf) {
        const int n = bn0 + wc * 32 + nf * 16 + lr;
        const float bvv = bias[n];
#pragma unroll
        for (int mh = 0; mh < 2; ++mh)
#pragma unroll
            for (int mf = 0; mf < 4; ++mf) {
                const f32x4 a = acc[mh * 4 + mf][nf];
                const int m0 = bm0 + mh * 128 + wr * 64 + mf * 16 + quad * 4;
#pragma unroll
                for (int r = 0; r < 4; ++r)
                    out[(size_t)(m0 + r) * Cc + n] = a[r] + bvv;
            }
    }
}

// ---------------- flash attention: 64-row Q-tiles, 4 blocks/CU -----------
// (unchanged from round 2)
__global__ __launch_bounds__(256, 4) void attn(const unsigned short* __restrict__ q,
                                               const unsigned short* __restrict__ k,
                                               const unsigned short* __restrict__ vt,
                                               unsigned short* __restrict__ y) {
    __shared__ unsigned short sK[2][64 * 64];
    __shared__ unsigned short sV[2][64 * 64];
    __shared__ unsigned short sP[4][16 * 64];

    const int tid  = threadIdx.x;
    const int wid  = tid >> 6;
    const int lane = tid & 63;
    const int quad = lane >> 4;
    const int lr   = lane & 15;

    const int bh = blockIdx.x;            // head
    const int qx = blockIdx.y;            // 0..15
    const size_t headq = (size_t)bh * Tt * HDd;
    const unsigned short* kg = k + headq;
    const unsigned short* vg = vt + headq;
    const int b = bh >> 4, h = bh & 15;

    const int g_r = lane >> 3;                       // 0..7
    const int g_c = ((lane & 7) ^ g_r) * 8;          // pre-swizzled src col
    const unsigned short* kst = kg + (size_t)(wid * 16 + g_r) * HDd + g_c;
    const unsigned short* vst = vg + (size_t)(wid * 16 + g_r) * Tt + g_c;
    unsigned short* dK0 = sK[0] + wid * 1024;
    unsigned short* dK1 = sK[1] + wid * 1024;
    unsigned short* dV0 = sV[0] + wid * 1024;
    unsigned short* dV1 = sV[1] + wid * 1024;

#define STAGE_KV(BUF, KB)                                                   \
    do {                                                                    \
        unsigned short* dK = (BUF) ? dK1 : dK0;                             \
        unsigned short* dV = (BUF) ? dV1 : dV0;                             \
        ASYNC16(kst + (size_t)(KB) * HDd,       dK);                        \
        ASYNC16(kst + (size_t)((KB) + 8) * HDd, dK + 512);                  \
        ASYNC16(vst + (KB),                     dV);                        \
        ASYNC16(vst + (size_t)8 * Tt + (KB),    dV + 512);                  \
    } while (0)

    const int fr_off = lr * 64 + ((quad ^ (lr & 7)) * 8);
    const int hq8 = (((lr >> 3) ^ ((quad & 1) << 2)) * 8);
    const int pwb = quad * 256 + (lr & 7);
    unsigned short* sPw = sP[wid];

    const f32x4 zero = {0.f, 0.f, 0.f, 0.f};

    for (int pass = 0; pass < 2; ++pass) {
        const int qt = pass ? (31 - qx) : qx;
        const int qb = qt * 64;
        const int ntiles = qt + 1;

        const unsigned short* qp = q + headq + (size_t)(qb + wid * 16 + lr) * HDd;
        const short8 qf0 = *(const short8*)(qp + quad * 8);
        const short8 qf1 = *(const short8*)(qp + 32 + quad * 8);

        f32x4 o[4];
        float l_run[4];
#pragma unroll
        for (int i = 0; i < 4; i++) { o[i] = zero; l_run[i] = 0.f; }

        STAGE_KV(0, 0);
        __syncthreads();

        for (int kt = 0; kt < ntiles; ++kt) {
            const int cur = kt & 1;
            if (kt + 1 < ntiles) STAGE_KV(cur ^ 1, (kt + 1) * 64);

            const unsigned short* bK = sK[cur];
            const unsigned short* bV = sV[cur];

            short8 kf[4][2];
#pragma unroll
            for (int nt = 0; nt < 4; nt++) {
                kf[nt][0] = *(const short8*)(bK + nt * 1024 + fr_off);
                kf[nt][1] = *(const short8*)(bK + nt * 1024 + (fr_off ^ 32));
            }

            f32x4 sc[4];
            __builtin_amdgcn_s_setprio(1);
#pragma unroll
            for (int nt = 0; nt < 4; nt++) {
                f32x4 a = __builtin_amdgcn_mfma_f32_16x16x32_bf16(qf0, kf[nt][0], zero, 0, 0, 0);
                sc[nt]  = __builtin_amdgcn_mfma_f32_16x16x32_bf16(qf1, kf[nt][1], a, 0, 0, 0);
            }
            __builtin_amdgcn_s_setprio(0);

            short8 vf[4][2];
#pragma unroll
            for (int nt = 0; nt < 4; nt++) {
                vf[nt][0] = *(const short8*)(bV + nt * 1024 + fr_off);
                vf[nt][1] = *(const short8*)(bV + nt * 1024 + (fr_off ^ 32));
            }

            if (kt == qt) {
#pragma unroll
                for (int nt = 0; nt < 4; nt++)
#pragma unroll
                    for (int r = 0; r < 4; r++)
                        sc[nt][r] = (nt * 16 + lr <= wid * 16 + quad * 4 + r)
                                        ? sc[nt][r] : -INFINITY;
            }

#pragma unroll
            for (int nt = 0; nt < 4; nt++)
#pragma unroll
                for (int r = 0; r < 4; r++) {
                    const float p = fast_exp2(sc[nt][r]);
                    l_run[r] += p;
                    sPw[pwb + r * 64 + ((nt * 16 ^ r * 8) ^ hq8)] = f32_bf16_rn(p);
                }

            const short8 pa0 = *(const short8*)(sPw + fr_off);
            const short8 pa1 = *(const short8*)(sPw + (fr_off ^ 32));

            __builtin_amdgcn_s_setprio(1);
#pragma unroll
            for (int nt = 0; nt < 4; nt++) {
                o[nt] = __builtin_amdgcn_mfma_f32_16x16x32_bf16(pa0, vf[nt][0], o[nt], 0, 0, 0);
                o[nt] = __builtin_amdgcn_mfma_f32_16x16x32_bf16(pa1, vf[nt][1], o[nt], 0, 0, 0);
            }
            __builtin_amdgcn_s_setprio(0);

            __syncthreads();
        }

#pragma unroll
        for (int r = 0; r < 4; r++) {
            float ls = l_run[r];
            ls += __shfl_xor(ls, 1);
            ls += __shfl_xor(ls, 2);
            ls += __shfl_xor(ls, 4);
            ls += __shfl_xor(ls, 8);
            const float inv = 1.0f / ls;
            const int t = qb + wid * 16 + quad * 4 + r;
#pragma unroll
            for (int nt = 0; nt < 4; nt++) {
                const int dim = nt * 16 + lr;
                y[((size_t)(b * Tt + t)) * Cc + h * HDd + dim] =
                    f32_bf16_rn(o[nt][r] * inv);
            }
        }
    }
#undef STAGE_KV
}

// ---------------- launch ----------------
extern "C" void kernel_launch(void* const* d_in, const int* in_sizes, int n_in,
                              void* d_out, int out_size, void* d_ws, size_t ws_size,
                              hipStream_t stream) {
    const float* x  = (const float*)d_in[0];
    const float* Wk = (const float*)d_in[1];
    const float* bk = (const float*)d_in[2];
    const float* Wq = (const float*)d_in[3];
    const float* bq = (const float*)d_in[4];
    const float* Wv = (const float*)d_in[5];
    const float* bv = (const float*)d_in[6];
    const float* Wp = (const float*)d_in[7];
    const float* bp = (const float*)d_in[8];
    float* out = (float*)d_out;

    char* ws = (char*)d_ws;
    size_t off = 0;
    auto alloc = [&](size_t bytes) { char* p = ws + off; off += bytes; return p; };
    const size_t MK = (size_t)8192 * 1024;
    const size_t NK = (size_t)1024 * 1024;
    unsigned short* xb   = (unsigned short*)alloc(MK * 2);
    unsigned short* Wcat = (unsigned short*)alloc(3 * NK * 2);  // q|k|v contiguous
    unsigned short* Wqb  = Wcat;
    unsigned short* Wkb  = Wcat + NK;
    unsigned short* Wvb  = Wcat + 2 * NK;
    unsigned short* Wpb  = (unsigned short*)alloc(NK * 2);
    unsigned short* qh   = (unsigned short*)alloc(MK * 2);  // [B,H,T,HD], pre-scaled
    unsigned short* kh   = (unsigned short*)alloc(MK * 2);  // [B,H,T,HD]
    unsigned short* vth  = (unsigned short*)alloc(MK * 2);  // [B,H,HD,T]
    unsigned short* ya   = (unsigned short*)alloc(MK * 2);  // [B,T,C]

    static bool lds_attr_set = false;
    if (!lds_attr_set) {
        (void)hipFuncSetAttribute((const void*)gemm_qkv8,
                                  hipFuncAttributeMaxDynamicSharedMemorySize,
                                  131072);
        (void)hipFuncSetAttribute((const void*)gemm_proj8,
                                  hipFuncAttributeMaxDynamicSharedMemorySize,
                                  98304);
        lds_attr_set = true;
    }

    cvt_all<<<12288, 256, 0, stream>>>(x, Wq, Wk, Wv, Wp, xb, Wqb, Wkb, Wvb, Wpb);

    gemm_qkv8<<<dim3(12, 32), 512, 131072, stream>>>(xb, Wcat, bq, bk, bv, qh, kh, vth);

    attn<<<dim3(64, 16), 256, 0, stream>>>(qh, kh, vth, ya);

    gemm_proj8<<<dim3(8, 32), 512, 98304, stream>>>(ya, Wpb, bp, out);
}

// Round 6
// 243.417 us; speedup vs baseline: 1.1474x; 1.0147x over previous
//
#include <hip/hip_runtime.h>
#include <hip/hip_bf16.h>
#include <cmath>

#define Tt 2048
#define Cc 1024
#define Hh 16
#define HDd 64

typedef __attribute__((ext_vector_type(8))) short short8;
typedef __attribute__((ext_vector_type(4))) float f32x4;

// async global->LDS, 16B per lane; lds base must be wave-uniform
#define ASYNC16(gp, lp)                                       \
    __builtin_amdgcn_global_load_lds(                         \
        (const __attribute__((address_space(1))) void*)(gp),  \
        (__attribute__((address_space(3))) void*)(lp), 16, 0, 0)

__device__ __forceinline__ unsigned short f32_bf16(float f) {
    unsigned u = __float_as_uint(f);
    u += 0x7FFF + ((u >> 16) & 1);
    return (unsigned short)(u >> 16);
}
// 2-op round-to-nearest (ties away) — fine for finite values
__device__ __forceinline__ unsigned short f32_bf16_rn(float f) {
    return (unsigned short)((__float_as_uint(f) + 0x8000u) >> 16);
}
__device__ __forceinline__ float fast_exp2(float x) {
#if __has_builtin(__builtin_amdgcn_exp2f)
    return __builtin_amdgcn_exp2f(x);
#else
    return exp2f(x);
#endif
}

// ---------------- fp32 -> bf16 convert: x + all 4 weights, one launch ----
__global__ __launch_bounds__(256) void cvt_all(
    const float* __restrict__ x, const float* __restrict__ a,
    const float* __restrict__ b, const float* __restrict__ c,
    const float* __restrict__ d, unsigned short* __restrict__ ox,
    unsigned short* __restrict__ oa, unsigned short* __restrict__ ob,
    unsigned short* __restrict__ oc, unsigned short* __restrict__ od) {
    const int id = blockIdx.x * 256 + threadIdx.x;
    const float* src; unsigned short* dst; int sub;
    if (id < 2097152) {
        src = x; dst = ox; sub = id;
    } else {
        const int wi = id - 2097152;
        const int which = wi >> 18;
        sub = wi & 262143;
        if (which == 0)      { src = a; dst = oa; }
        else if (which == 1) { src = b; dst = ob; }
        else if (which == 2) { src = c; dst = oc; }
        else                 { src = d; dst = od; }
    }
    float4 v = ((const float4*)src)[sub];
    ushort4 o;
    o.x = f32_bf16(v.x); o.y = f32_bf16(v.y);
    o.z = f32_bf16(v.z); o.w = f32_bf16(v.w);
    ((ushort4*)dst)[sub] = o;
}

// ---------------- Q|K GEMM: 256x256 4-phase counted-vmcnt ---------------
// Round-4/5 change: N range split. This kernel now covers N-cols 0..2047
// (Q and K panels) -> grid (8,32) = 256 blocks = EXACTLY one residency
// generation at 1 block/CU (was 384 blocks -> 1.5 gens, 25% CU-idle;
// the gen2 dilution showed as Occupancy 15.8%, MfmaUtil 28%).
// V (cols 2048..3071) moves to gemm_v8 (proj8-geometry clone, also 1 gen).
__global__ __launch_bounds__(512, 2) void gemm_qkv8(
    const unsigned short* __restrict__ A,
    const unsigned short* __restrict__ Wcat,
    const float* __restrict__ bq, const float* __restrict__ bk,
    const float* __restrict__ bv,
    unsigned short* __restrict__ qout, unsigned short* __restrict__ kout,
    unsigned short* __restrict__ vout) {
    extern __shared__ unsigned short lds[];

    const int tid  = threadIdx.x;
    const int wid  = tid >> 6;      // 0..7
    const int lane = tid & 63;
    const int quad = lane >> 4;     // 0..3
    const int lr   = lane & 15;
    const int wr   = wid >> 2;      // 0..1  (M)
    const int wc   = wid & 3;       // 0..3  (N)

    // slab swizzle (proj8's map): xcd = id%8 owns 4 M-rows x all 8 N-cols
    const int id   = blockIdx.y * 8 + blockIdx.x;
    const int xcd  = id & 7;
    const int rank = id >> 3;                 // 0..31
    const int by   = xcd * 4 + (rank >> 3);   // 0..31
    const int bx   = rank & 7;                // 0..7
    const int bm0  = by * 256;
    const int bn0  = bx * 256;                // 0..1792 (Q|K only)

    const int srow  = wid * 8 + (lane >> 3);            // 0..63
    const int scol  = ((lane & 7) ^ (lane >> 3)) * 8;   // swizzled src col
    const int sldso = wid * 512;                        // shorts

    const int a_r   = wr * 64 + lr;
    const int b_r   = wc * 32 + lr;
    const int slot0 = (quad ^ (lr & 7)) * 8;            // ks=0, shorts
    const int slot1 = ((quad ^ 4) ^ (lr & 7)) * 8;      // ks=1

    f32x4 acc[8][4];
    const f32x4 zero = {0.f, 0.f, 0.f, 0.f};
#pragma unroll
    for (int i = 0; i < 8; ++i)
#pragma unroll
        for (int j = 0; j < 4; ++j) acc[i][j] = zero;

    short8 areg[4][2];
    short8 breg[2][2][2];

#define STG(S, BUF, REG, GB, GROW)                                          \
    do {                                                                    \
        if ((S) < 16) {                                                     \
            unsigned short* lb = lds + ((BUF) * 4 + (REG)) * 8192 + sldso;  \
            const unsigned short* gp =                                      \
                (GB) + (size_t)((GROW) + srow) * Cc + (S) * 64 + scol;      \
            ASYNC16(gp, lb);                                                \
            ASYNC16(gp + (size_t)64 * Cc, lb + 4096);                       \
        }                                                                   \
    } while (0)

#define LDA(mh)                                                             \
    do {                                                                    \
        const unsigned short* ab = bufb + (mh) * 8192;                      \
        _Pragma("unroll") for (int mf = 0; mf < 4; ++mf) {                  \
            areg[mf][0] = *(const short8*)(ab + (a_r + mf * 16) * 64 + slot0); \
            areg[mf][1] = *(const short8*)(ab + (a_r + mf * 16) * 64 + slot1); \
        }                                                                   \
    } while (0)

#define LDB(nh)                                                             \
    do {                                                                    \
        const unsigned short* bb = bufb + (2 + (nh)) * 8192;                \
        _Pragma("unroll") for (int nf = 0; nf < 2; ++nf) {                  \
            breg[nh][nf][0] = *(const short8*)(bb + (b_r + nf * 16) * 64 + slot0); \
            breg[nh][nf][1] = *(const short8*)(bb + (b_r + nf * 16) * 64 + slot1); \
        }                                                                   \
    } while (0)

#define MFMA_PHASE(mh, nh)                                                  \
    _Pragma("unroll") for (int mf = 0; mf < 4; ++mf)                        \
    _Pragma("unroll") for (int nf = 0; nf < 2; ++nf) {                      \
        acc[(mh)*4+mf][(nh)*2+nf] = __builtin_amdgcn_mfma_f32_16x16x32_bf16( \
            areg[mf][0], breg[nh][nf][0], acc[(mh)*4+mf][(nh)*2+nf], 0,0,0); \
        acc[(mh)*4+mf][(nh)*2+nf] = __builtin_amdgcn_mfma_f32_16x16x32_bf16( \
            areg[mf][1], breg[nh][nf][1], acc[(mh)*4+mf][(nh)*2+nf], 0,0,0); \
    }

#define TILE(T, BC, WN)                                                     \
    {                                                                       \
        const unsigned short* bufb = lds + (BC) * 32768;                    \
        LDA(0);                                                             \
        LDB(0);                                                             \
        STG((T) + 1, (BC) ^ 1, 1, A, bm0 + 128);                            \
        __builtin_amdgcn_s_barrier();                                       \
        asm volatile("s_waitcnt lgkmcnt(0)" ::: "memory");                  \
        __builtin_amdgcn_s_setprio(1);                                      \
        MFMA_PHASE(0, 0);                                                   \
        __builtin_amdgcn_s_setprio(0);                                      \
        __builtin_amdgcn_s_barrier();                                       \
        LDB(1);                                                             \
        STG((T) + 1, (BC) ^ 1, 3, Wcat, bn0 + 128);                         \
        __builtin_amdgcn_s_barrier();                                       \
        asm volatile("s_waitcnt lgkmcnt(0)" ::: "memory");                  \
        __builtin_amdgcn_s_setprio(1);                                      \
        MFMA_PHASE(0, 1);                                                   \
        __builtin_amdgcn_s_setprio(0);                                      \
        __builtin_amdgcn_s_barrier();                                       \
        LDA(1);                                                             \
        STG((T) + 2, (BC), 0, A, bm0);                                      \
        __builtin_amdgcn_s_barrier();                                       \
        asm volatile("s_waitcnt lgkmcnt(0)" ::: "memory");                  \
        __builtin_amdgcn_s_setprio(1);                                      \
        MFMA_PHASE(1, 0);                                                   \
        __builtin_amdgcn_s_setprio(0);                                      \
        __builtin_amdgcn_s_barrier();                                       \
        STG((T) + 2, (BC), 2, Wcat, bn0);                                   \
        __builtin_amdgcn_s_barrier();                                       \
        __builtin_amdgcn_s_setprio(1);                                      \
        MFMA_PHASE(1, 1);                                                   \
        __builtin_amdgcn_s_setprio(0);                                      \
        asm volatile("s_waitcnt vmcnt(" #WN ")" ::: "memory");              \
        __builtin_amdgcn_s_barrier();                                       \
    }

    STG(0, 0, 0, A, bm0);
    STG(0, 0, 1, A, bm0 + 128);
    STG(0, 0, 2, Wcat, bn0);
    STG(0, 0, 3, Wcat, bn0 + 128);
    STG(1, 1, 0, A, bm0);
    STG(1, 1, 2, Wcat, bn0);
    asm volatile("s_waitcnt vmcnt(4)" ::: "memory");
    __builtin_amdgcn_s_barrier();

    for (int t2 = 0; t2 < 7; ++t2) {
        const int T0 = t2 * 2;
        TILE(T0, 0, 4);
        TILE(T0 + 1, 1, 4);
    }
    TILE(14, 0, 0);
    TILE(15, 1, 0);

#undef TILE
#undef MFMA_PHASE
#undef LDB
#undef LDA
#undef STG

    const int which = bn0 >> 10;  // 0=q 1=k (v handled by gemm_v8)
    const float* bias = (which == 0) ? bq : bk;
    unsigned short* outp = (which == 0) ? qout : kout;
    const float scale = (which == 0) ? 0.1803368801111204f : 1.0f;  // 0.125*log2e
    const int nb = bn0 & 1023;
    (void)bv; (void)vout;

#pragma unroll
    for (int nh = 0; nh < 2; ++nh)
#pragma unroll
        for (int nf = 0; nf < 2; ++nf) {
            const int nl = nb + nh * 128 + wc * 32 + nf * 16 + lr;
            const float bvv = bias[nl];
            const int h = nl >> 6, hd = nl & 63;
#pragma unroll
            for (int mh = 0; mh < 2; ++mh)
#pragma unroll
                for (int mf = 0; mf < 4; ++mf) {
                    const f32x4 a = acc[mh * 4 + mf][nh * 2 + nf];
                    const int m0 = bm0 + mh * 128 + wr * 64 + mf * 16 + quad * 4;
                    const int b = m0 >> 11, t0 = m0 & 2047;
#pragma unroll
                    for (int r = 0; r < 4; ++r) {
                        outp[(((size_t)(b * Hh + h)) * Tt + t0 + r) * HDd + hd] =
                            f32_bf16_rn((a[r] + bvv) * scale);
                    }
                }
        }
}

// ---------------- V GEMM: 256x128 2-phase (gemm_proj8 clone) -------------
// Covers N-cols 2048..3071 of Wcat (= the V panel) as 32x8 tiles of
// 256x128 -> 256 blocks = exactly one generation. Structure identical to
// the verified gemm_proj8; only the W row offset (+2048) and the v-mode
// bf16 [B,H,HD,T] ushort4 epilogue differ.
__global__ __launch_bounds__(512, 2) void gemm_v8(
    const unsigned short* __restrict__ A,
    const unsigned short* __restrict__ Wcat,
    const float* __restrict__ bv,
    unsigned short* __restrict__ vout) {
    extern __shared__ unsigned short lds[];

    const int tid  = threadIdx.x;
    const int wid  = tid >> 6;
    const int lane = tid & 63;
    const int quad = lane >> 4;
    const int lr   = lane & 15;
    const int wr   = wid >> 2;      // 0..1
    const int wc   = wid & 3;       // 0..3

    const int id   = blockIdx.y * 8 + blockIdx.x;
    const int xcd  = id & 7;
    const int rank = id >> 3;
    const int by   = xcd * 4 + (rank >> 3);  // 0..31
    const int bx   = rank & 7;               // 0..7
    const int bm0  = by * 256;
    const int wrow0 = 2048 + bx * 128;       // row in Wcat

    const int srow  = wid * 8 + (lane >> 3);
    const int scol  = ((lane & 7) ^ (lane >> 3)) * 8;
    const int sldso = wid * 512;

    const int a_r   = wr * 64 + lr;
    const int b_r2  = (wc & 1) * 32 + lr;
    const int breg_off = 16384 + (wc >> 1) * 4096;
    const int slot0 = (quad ^ (lr & 7)) * 8;
    const int slot1 = ((quad ^ 4) ^ (lr & 7)) * 8;

    f32x4 acc[8][2];
    const f32x4 zero = {0.f, 0.f, 0.f, 0.f};
#pragma unroll
    for (int i = 0; i < 8; ++i)
#pragma unroll
        for (int j = 0; j < 2; ++j) acc[i][j] = zero;

    short8 areg[4][2];
    short8 breg[2][2];

#define STGAV(S, BUF, REG_OFF, GROW)                                        \
    do {                                                                    \
        if ((S) < 16) {                                                     \
            unsigned short* lb = lds + (BUF) * 24576 + (REG_OFF) + sldso;   \
            const unsigned short* gp =                                      \
                A + (size_t)(bm0 + (GROW) + srow) * Cc + (S) * 64 + scol;   \
            ASYNC16(gp, lb);                                                \
            ASYNC16(gp + (size_t)64 * Cc, lb + 4096);                       \
        }                                                                   \
    } while (0)

#define STGBV(S, BUF, REG_OFF, NROW)                                        \
    do {                                                                    \
        if ((S) < 16) {                                                     \
            unsigned short* lb = lds + (BUF) * 24576 + (REG_OFF) + sldso;   \
            const unsigned short* gp =                                      \
                Wcat + (size_t)(wrow0 + (NROW) + srow) * Cc + (S) * 64 + scol; \
            ASYNC16(gp, lb);                                                \
        }                                                                   \
    } while (0)

#define LDA_V(mh)                                                           \
    do {                                                                    \
        const unsigned short* ab = bufb + (mh) * 8192;                      \
        _Pragma("unroll") for (int mf = 0; mf < 4; ++mf) {                  \
            areg[mf][0] = *(const short8*)(ab + (a_r + mf * 16) * 64 + slot0); \
            areg[mf][1] = *(const short8*)(ab + (a_r + mf * 16) * 64 + slot1); \
        }                                                                   \
    } while (0)

#define LDB_V                                                               \
    do {                                                                    \
        const unsigned short* bb = bufb + breg_off;                         \
        _Pragma("unroll") for (int nf = 0; nf < 2; ++nf) {                  \
            breg[nf][0] = *(const short8*)(bb + (b_r2 + nf * 16) * 64 + slot0); \
            breg[nf][1] = *(const short8*)(bb + (b_r2 + nf * 16) * 64 + slot1); \
        }                                                                   \
    } while (0)

#define MFMA_V(mh)                                                          \
    _Pragma("unroll") for (int mf = 0; mf < 4; ++mf)                        \
    _Pragma("unroll") for (int nf = 0; nf < 2; ++nf) {                      \
        acc[(mh)*4+mf][nf] = __builtin_amdgcn_mfma_f32_16x16x32_bf16(       \
            areg[mf][0], breg[nf][0], acc[(mh)*4+mf][nf], 0, 0, 0);         \
        acc[(mh)*4+mf][nf] = __builtin_amdgcn_mfma_f32_16x16x32_bf16(       \
            areg[mf][1], breg[nf][1], acc[(mh)*4+mf][nf], 0, 0, 0);         \
    }

#define TILE_V(T, BC, WN)                                                   \
    {                                                                       \
        const unsigned short* bufb = lds + (BC) * 24576;                    \
        LDA_V(0);                                                           \
        LDB_V;                                                              \
        STGAV((T) + 1, (BC) ^ 1, 8192, 128);                                \
        STGBV((T) + 1, (BC) ^ 1, 20480, 64);                                \
        __builtin_amdgcn_s_barrier();                                       \
        asm volatile("s_waitcnt lgkmcnt(0)" ::: "memory");                  \
        __builtin_amdgcn_s_setprio(1);                                      \
        MFMA_V(0);                                                          \
        __builtin_amdgcn_s_setprio(0);                                      \
        __builtin_amdgcn_s_barrier();                                       \
        LDA_V(1);                                                           \
        STGAV((T) + 2, (BC), 0, 0);                                         \
        STGBV((T) + 2, (BC), 16384, 0);                                     \
        __builtin_amdgcn_s_barrier();                                       \
        asm volatile("s_waitcnt lgkmcnt(0)" ::: "memory");                  \
        __builtin_amdgcn_s_setprio(1);                                      \
        MFMA_V(1);                                                          \
        __builtin_amdgcn_s_setprio(0);                                      \
        asm volatile("s_waitcnt vmcnt(" #WN ")" ::: "memory");              \
        __builtin_amdgcn_s_barrier();                                       \
    }

    STGAV(0, 0, 0, 0);
    STGAV(0, 0, 8192, 128);
    STGBV(0, 0, 16384, 0);
    STGBV(0, 0, 20480, 64);
    STGAV(1, 1, 0, 0);
    STGBV(1, 1, 16384, 0);
    asm volatile("s_waitcnt vmcnt(3)" ::: "memory");
    __builtin_amdgcn_s_barrier();

    for (int t2 = 0; t2 < 7; ++t2) {
        const int T0 = t2 * 2;
        TILE_V(T0, 0, 3);
        TILE_V(T0 + 1, 1, 3);
    }
    TILE_V(14, 0, 0);
    TILE_V(15, 1, 0);

#undef TILE_V
#undef MFMA_V
#undef LDB_V
#undef LDA_V
#undef STGBV
#undef STGAV

    // v epilogue: bf16 [B,H,HD,T], ushort4 along T
#pragma unroll
    for (int nf = 0; nf < 2; ++nf) {
        const int nl = (wrow0 - 2048) + wc * 32 + nf * 16 + lr;  // 0..1023
        const float bvv = bv[nl];
        const int h = nl >> 6, hd = nl & 63;
#pragma unroll
        for (int mh = 0; mh < 2; ++mh)
#pragma unroll
            for (int mf = 0; mf < 4; ++mf) {
                const f32x4 a = acc[mh * 4 + mf][nf];
                const int m0 = bm0 + mh * 128 + wr * 64 + mf * 16 + quad * 4;
                const int b = m0 >> 11, t0 = m0 & 2047;
                ushort4 pk;
                pk.x = f32_bf16_rn(a[0] + bvv);
                pk.y = f32_bf16_rn(a[1] + bvv);
                pk.z = f32_bf16_rn(a[2] + bvv);
                pk.w = f32_bf16_rn(a[3] + bvv);
                *(ushort4*)(vout + (((size_t)(b * Hh + h)) * HDd + hd) * Tt + t0) = pk;
            }
    }
}

// ---------------- output projection GEMM: 256x128 2-phase template -------
// (unchanged from round 3 — verified)
__global__ __launch_bounds__(512, 2) void gemm_proj8(
    const unsigned short* __restrict__ A,
    const unsigned short* __restrict__ W,
    const float* __restrict__ bias,
    float* __restrict__ out) {
    extern __shared__ unsigned short lds[];

    const int tid  = threadIdx.x;
    const int wid  = tid >> 6;
    const int lane = tid & 63;
    const int quad = lane >> 4;
    const int lr   = lane & 15;
    const int wr   = wid >> 2;      // 0..1
    const int wc   = wid & 3;       // 0..3

    const int id   = blockIdx.y * 8 + blockIdx.x;
    const int xcd  = id & 7;
    const int rank = id >> 3;          // 0..31
    const int by   = xcd * 4 + (rank >> 3);  // 0..31
    const int bx   = rank & 7;               // 0..7
    const int bm0  = by * 256;
    const int bn0  = bx * 128;

    const int srow  = wid * 8 + (lane >> 3);
    const int scol  = ((lane & 7) ^ (lane >> 3)) * 8;
    const int sldso = wid * 512;

    const int a_r   = wr * 64 + lr;
    const int b_r2  = (wc & 1) * 32 + lr;     // row within own B region
    const int breg_off = 16384 + (wc >> 1) * 4096;  // wave's B region
    const int slot0 = (quad ^ (lr & 7)) * 8;
    const int slot1 = ((quad ^ 4) ^ (lr & 7)) * 8;

    f32x4 acc[8][2];
    const f32x4 zero = {0.f, 0.f, 0.f, 0.f};
#pragma unroll
    for (int i = 0; i < 8; ++i)
#pragma unroll
        for (int j = 0; j < 2; ++j) acc[i][j] = zero;

    short8 areg[4][2];
    short8 breg[2][2];

#define STGA(S, BUF, REG_OFF, GROW)                                         \
    do {                                                                    \
        if ((S) < 16) {                                                     \
            unsigned short* lb = lds + (BUF) * 24576 + (REG_OFF) + sldso;   \
            const unsigned short* gp =                                      \
                A + (size_t)(bm0 + (GROW) + srow) * Cc + (S) * 64 + scol;   \
            ASYNC16(gp, lb);                                                \
            ASYNC16(gp + (size_t)64 * Cc, lb + 4096);                       \
        }                                                                   \
    } while (0)

#define STGB(S, BUF, REG_OFF, NROW)                                         \
    do {                                                                    \
        if ((S) < 16) {                                                     \
            unsigned short* lb = lds + (BUF) * 24576 + (REG_OFF) + sldso;   \
            const unsigned short* gp =                                      \
                W + (size_t)(bn0 + (NROW) + srow) * Cc + (S) * 64 + scol;   \
            ASYNC16(gp, lb);                                                \
        }                                                                   \
    } while (0)

#define LDA_P(mh)                                                           \
    do {                                                                    \
        const unsigned short* ab = bufb + (mh) * 8192;                      \
        _Pragma("unroll") for (int mf = 0; mf < 4; ++mf) {                  \
            areg[mf][0] = *(const short8*)(ab + (a_r + mf * 16) * 64 + slot0); \
            areg[mf][1] = *(const short8*)(ab + (a_r + mf * 16) * 64 + slot1); \
        }                                                                   \
    } while (0)

#define LDB_P                                                               \
    do {                                                                    \
        const unsigned short* bb = bufb + breg_off;                         \
        _Pragma("unroll") for (int nf = 0; nf < 2; ++nf) {                  \
            breg[nf][0] = *(const short8*)(bb + (b_r2 + nf * 16) * 64 + slot0); \
            breg[nf][1] = *(const short8*)(bb + (b_r2 + nf * 16) * 64 + slot1); \
        }                                                                   \
    } while (0)

#define MFMA_P(mh)                                                          \
    _Pragma("unroll") for (int mf = 0; mf < 4; ++mf)                        \
    _Pragma("unroll") for (int nf = 0; nf < 2; ++nf) {                      \
        acc[(mh)*4+mf][nf] = __builtin_amdgcn_mfma_f32_16x16x32_bf16(       \
            areg[mf][0], breg[nf][0], acc[(mh)*4+mf][nf], 0, 0, 0);         \
        acc[(mh)*4+mf][nf] = __builtin_amdgcn_mfma_f32_16x16x32_bf16(       \
            areg[mf][1], breg[nf][1], acc[(mh)*4+mf][nf], 0, 0, 0);         \
    }

#define TILE_P(T, BC, WN)                                                   \
    {                                                                       \
        const unsigned short* bufb = lds + (BC) * 24576;                    \
        LDA_P(0);                                                           \
        LDB_P;                                                              \
        STGA((T) + 1, (BC) ^ 1, 8192, 128);                                 \
        STGB((T) + 1, (BC) ^ 1, 20480, 64);                                 \
        __builtin_amdgcn_s_barrier();                                       \
        asm volatile("s_waitcnt lgkmcnt(0)" ::: "memory");                  \
        __builtin_amdgcn_s_setprio(1);                                      \
        MFMA_P(0);                                                          \
        __builtin_amdgcn_s_setprio(0);                                      \
        __builtin_amdgcn_s_barrier();                                       \
        LDA_P(1);                                                           \
        STGA((T) + 2, (BC), 0, 0);                                          \
        STGB((T) + 2, (BC), 16384, 0);                                      \
        __builtin_amdgcn_s_barrier();                                       \
        asm volatile("s_waitcnt lgkmcnt(0)" ::: "memory");                  \
        __builtin_amdgcn_s_setprio(1);                                      \
        MFMA_P(1);                                                          \
        __builtin_amdgcn_s_setprio(0);                                      \
        asm volatile("s_waitcnt vmcnt(" #WN ")" ::: "memory");              \
        __builtin_amdgcn_s_barrier();                                       \
    }

    STGA(0, 0, 0, 0);
    STGA(0, 0, 8192, 128);
    STGB(0, 0, 16384, 0);
    STGB(0, 0, 20480, 64);
    STGA(1, 1, 0, 0);
    STGB(1, 1, 16384, 0);
    asm volatile("s_waitcnt vmcnt(3)" ::: "memory");
    __builtin_amdgcn_s_barrier();

    for (int t2 = 0; t2 < 7; ++t2) {
        const int T0 = t2 * 2;
        TILE_P(T0, 0, 3);
        TILE_P(T0 + 1, 1, 3);
    }
    TILE_P(14, 0, 0);
    TILE_P(15, 1, 0);

#undef TILE_P
#undef MFMA_P
#undef LDB_P
#undef LDA_P
#undef STGB
#undef STGA

#pragma unroll
    for (int nf = 0; nf < 2; ++nf) {
        const int n = bn0 + wc * 32 + nf * 16 + lr;
        const float bvv = bias[n];
#pragma unroll
        for (int mh = 0; mh < 2; ++mh)
#pragma unroll
            for (int mf = 0; mf < 4; ++mf) {
                const f32x4 a = acc[mh * 4 + mf][nf];
                const int m0 = bm0 + mh * 128 + wr * 64 + mf * 16 + quad * 4;
#pragma unroll
                for (int r = 0; r < 4; ++r)
                    out[(size_t)(m0 + r) * Cc + n] = a[r] + bvv;
            }
    }
}

// ---------------- flash attention: 64-row Q-tiles, 4 blocks/CU -----------
// (unchanged from round 2)
__global__ __launch_bounds__(256, 4) void attn(const unsigned short* __restrict__ q,
                                               const unsigned short* __restrict__ k,
                                               const unsigned short* __restrict__ vt,
                                               unsigned short* __restrict__ y) {
    __shared__ unsigned short sK[2][64 * 64];
    __shared__ unsigned short sV[2][64 * 64];
    __shared__ unsigned short sP[4][16 * 64];

    const int tid  = threadIdx.x;
    const int wid  = tid >> 6;
    const int lane = tid & 63;
    const int quad = lane >> 4;
    const int lr   = lane & 15;

    const int bh = blockIdx.x;            // head
    const int qx = blockIdx.y;            // 0..15
    const size_t headq = (size_t)bh * Tt * HDd;
    const unsigned short* kg = k + headq;
    const unsigned short* vg = vt + headq;
    const int b = bh >> 4, h = bh & 15;

    const int g_r = lane >> 3;                       // 0..7
    const int g_c = ((lane & 7) ^ g_r) * 8;          // pre-swizzled src col
    const unsigned short* kst = kg + (size_t)(wid * 16 + g_r) * HDd + g_c;
    const unsigned short* vst = vg + (size_t)(wid * 16 + g_r) * Tt + g_c;
    unsigned short* dK0 = sK[0] + wid * 1024;
    unsigned short* dK1 = sK[1] + wid * 1024;
    unsigned short* dV0 = sV[0] + wid * 1024;
    unsigned short* dV1 = sV[1] + wid * 1024;

#define STAGE_KV(BUF, KB)                                                   \
    do {                                                                    \
        unsigned short* dK = (BUF) ? dK1 : dK0;                             \
        unsigned short* dV = (BUF) ? dV1 : dV0;                             \
        ASYNC16(kst + (size_t)(KB) * HDd,       dK);                        \
        ASYNC16(kst + (size_t)((KB) + 8) * HDd, dK + 512);                  \
        ASYNC16(vst + (KB),                     dV);                        \
        ASYNC16(vst + (size_t)8 * Tt + (KB),    dV + 512);                  \
    } while (0)

    const int fr_off = lr * 64 + ((quad ^ (lr & 7)) * 8);
    const int hq8 = (((lr >> 3) ^ ((quad & 1) << 2)) * 8);
    const int pwb = quad * 256 + (lr & 7);
    unsigned short* sPw = sP[wid];

    const f32x4 zero = {0.f, 0.f, 0.f, 0.f};

    for (int pass = 0; pass < 2; ++pass) {
        const int qt = pass ? (31 - qx) : qx;
        const int qb = qt * 64;
        const int ntiles = qt + 1;

        const unsigned short* qp = q + headq + (size_t)(qb + wid * 16 + lr) * HDd;
        const short8 qf0 = *(const short8*)(qp + quad * 8);
        const short8 qf1 = *(const short8*)(qp + 32 + quad * 8);

        f32x4 o[4];
        float l_run[4];
#pragma unroll
        for (int i = 0; i < 4; i++) { o[i] = zero; l_run[i] = 0.f; }

        STAGE_KV(0, 0);
        __syncthreads();

        for (int kt = 0; kt < ntiles; ++kt) {
            const int cur = kt & 1;
            if (kt + 1 < ntiles) STAGE_KV(cur ^ 1, (kt + 1) * 64);

            const unsigned short* bK = sK[cur];
            const unsigned short* bV = sV[cur];

            short8 kf[4][2];
#pragma unroll
            for (int nt = 0; nt < 4; nt++) {
                kf[nt][0] = *(const short8*)(bK + nt * 1024 + fr_off);
                kf[nt][1] = *(const short8*)(bK + nt * 1024 + (fr_off ^ 32));
            }

            f32x4 sc[4];
            __builtin_amdgcn_s_setprio(1);
#pragma unroll
            for (int nt = 0; nt < 4; nt++) {
                f32x4 a = __builtin_amdgcn_mfma_f32_16x16x32_bf16(qf0, kf[nt][0], zero, 0, 0, 0);
                sc[nt]  = __builtin_amdgcn_mfma_f32_16x16x32_bf16(qf1, kf[nt][1], a, 0, 0, 0);
            }
            __builtin_amdgcn_s_setprio(0);

            short8 vf[4][2];
#pragma unroll
            for (int nt = 0; nt < 4; nt++) {
                vf[nt][0] = *(const short8*)(bV + nt * 1024 + fr_off);
                vf[nt][1] = *(const short8*)(bV + nt * 1024 + (fr_off ^ 32));
            }

            if (kt == qt) {
#pragma unroll
                for (int nt = 0; nt < 4; nt++)
#pragma unroll
                    for (int r = 0; r < 4; r++)
                        sc[nt][r] = (nt * 16 + lr <= wid * 16 + quad * 4 + r)
                                        ? sc[nt][r] : -INFINITY;
            }

#pragma unroll
            for (int nt = 0; nt < 4; nt++)
#pragma unroll
                for (int r = 0; r < 4; r++) {
                    const float p = fast_exp2(sc[nt][r]);
                    l_run[r] += p;
                    sPw[pwb + r * 64 + ((nt * 16 ^ r * 8) ^ hq8)] = f32_bf16_rn(p);
                }

            const short8 pa0 = *(const short8*)(sPw + fr_off);
            const short8 pa1 = *(const short8*)(sPw + (fr_off ^ 32));

            __builtin_amdgcn_s_setprio(1);
#pragma unroll
            for (int nt = 0; nt < 4; nt++) {
                o[nt] = __builtin_amdgcn_mfma_f32_16x16x32_bf16(pa0, vf[nt][0], o[nt], 0, 0, 0);
                o[nt] = __builtin_amdgcn_mfma_f32_16x16x32_bf16(pa1, vf[nt][1], o[nt], 0, 0, 0);
            }
            __builtin_amdgcn_s_setprio(0);

            __syncthreads();
        }

#pragma unroll
        for (int r = 0; r < 4; r++) {
            float ls = l_run[r];
            ls += __shfl_xor(ls, 1);
            ls += __shfl_xor(ls, 2);
            ls += __shfl_xor(ls, 4);
            ls += __shfl_xor(ls, 8);
            const float inv = 1.0f / ls;
            const int t = qb + wid * 16 + quad * 4 + r;
#pragma unroll
            for (int nt = 0; nt < 4; nt++) {
                const int dim = nt * 16 + lr;
                y[((size_t)(b * Tt + t)) * Cc + h * HDd + dim] =
                    f32_bf16_rn(o[nt][r] * inv);
            }
        }
    }
#undef STAGE_KV
}

// ---------------- launch ----------------
extern "C" void kernel_launch(void* const* d_in, const int* in_sizes, int n_in,
                              void* d_out, int out_size, void* d_ws, size_t ws_size,
                              hipStream_t stream) {
    const float* x  = (const float*)d_in[0];
    const float* Wk = (const float*)d_in[1];
    const float* bk = (const float*)d_in[2];
    const float* Wq = (const float*)d_in[3];
    const float* bq = (const float*)d_in[4];
    const float* Wv = (const float*)d_in[5];
    const float* bv = (const float*)d_in[6];
    const float* Wp = (const float*)d_in[7];
    const float* bp = (const float*)d_in[8];
    float* out = (float*)d_out;

    char* ws = (char*)d_ws;
    size_t off = 0;
    auto alloc = [&](size_t bytes) { char* p = ws + off; off += bytes; return p; };
    const size_t MK = (size_t)8192 * 1024;
    const size_t NK = (size_t)1024 * 1024;
    unsigned short* xb   = (unsigned short*)alloc(MK * 2);
    unsigned short* Wcat = (unsigned short*)alloc(3 * NK * 2);  // q|k|v contiguous
    unsigned short* Wqb  = Wcat;
    unsigned short* Wkb  = Wcat + NK;
    unsigned short* Wvb  = Wcat + 2 * NK;
    unsigned short* Wpb  = (unsigned short*)alloc(NK * 2);
    unsigned short* qh   = (unsigned short*)alloc(MK * 2);  // [B,H,T,HD], pre-scaled
    unsigned short* kh   = (unsigned short*)alloc(MK * 2);  // [B,H,T,HD]
    unsigned short* vth  = (unsigned short*)alloc(MK * 2);  // [B,H,HD,T]
    unsigned short* ya   = (unsigned short*)alloc(MK * 2);  // [B,T,C]

    static bool lds_attr_set = false;
    if (!lds_attr_set) {
        (void)hipFuncSetAttribute((const void*)gemm_qkv8,
                                  hipFuncAttributeMaxDynamicSharedMemorySize,
                                  131072);
        (void)hipFuncSetAttribute((const void*)gemm_v8,
                                  hipFuncAttributeMaxDynamicSharedMemorySize,
                                  98304);
        (void)hipFuncSetAttribute((const void*)gemm_proj8,
                                  hipFuncAttributeMaxDynamicSharedMemorySize,
                                  98304);
        lds_attr_set = true;
    }

    cvt_all<<<12288, 256, 0, stream>>>(x, Wq, Wk, Wv, Wp, xb, Wqb, Wkb, Wvb, Wpb);

    gemm_qkv8<<<dim3(8, 32), 512, 131072, stream>>>(xb, Wcat, bq, bk, bv, qh, kh, vth);
    gemm_v8<<<dim3(8, 32), 512, 98304, stream>>>(xb, Wcat, bv, vth);

    attn<<<dim3(64, 16), 256, 0, stream>>>(qh, kh, vth, ya);

    gemm_proj8<<<dim3(8, 32), 512, 98304, stream>>>(ya, Wpb, bp, out);
}

// Round 7
// 229.162 us; speedup vs baseline: 1.2188x; 1.0622x over previous
//
#include <hip/hip_runtime.h>
#include <hip/hip_bf16.h>
#include <cmath>

#define Tt 2048
#define Cc 1024
#define Hh 16
#define HDd 64

typedef __attribute__((ext_vector_type(8))) short short8;
typedef __attribute__((ext_vector_type(4))) float f32x4;
typedef __attribute__((ext_vector_type(16))) float f32x16;

// async global->LDS, 16B per lane; lds base must be wave-uniform
#define ASYNC16(gp, lp)                                       \
    __builtin_amdgcn_global_load_lds(                         \
        (const __attribute__((address_space(1))) void*)(gp),  \
        (__attribute__((address_space(3))) void*)(lp), 16, 0, 0)

__device__ __forceinline__ unsigned short f32_bf16(float f) {
    unsigned u = __float_as_uint(f);
    u += 0x7FFF + ((u >> 16) & 1);
    return (unsigned short)(u >> 16);
}
// 2-op round-to-nearest (ties away) — fine for finite values
__device__ __forceinline__ unsigned short f32_bf16_rn(float f) {
    return (unsigned short)((__float_as_uint(f) + 0x8000u) >> 16);
}
__device__ __forceinline__ float fast_exp2(float x) {
#if __has_builtin(__builtin_amdgcn_exp2f)
    return __builtin_amdgcn_exp2f(x);
#else
    return exp2f(x);
#endif
}

// ---------------- fp32 -> bf16 convert: x + all 4 weights, one launch ----
__global__ __launch_bounds__(256) void cvt_all(
    const float* __restrict__ x, const float* __restrict__ a,
    const float* __restrict__ b, const float* __restrict__ c,
    const float* __restrict__ d, unsigned short* __restrict__ ox,
    unsigned short* __restrict__ oa, unsigned short* __restrict__ ob,
    unsigned short* __restrict__ oc, unsigned short* __restrict__ od) {
    const int id = blockIdx.x * 256 + threadIdx.x;
    const float* src; unsigned short* dst; int sub;
    if (id < 2097152) {
        src = x; dst = ox; sub = id;
    } else {
        const int wi = id - 2097152;
        const int which = wi >> 18;
        sub = wi & 262143;
        if (which == 0)      { src = a; dst = oa; }
        else if (which == 1) { src = b; dst = ob; }
        else if (which == 2) { src = c; dst = oc; }
        else                 { src = d; dst = od; }
    }
    float4 v = ((const float4*)src)[sub];
    ushort4 o;
    o.x = f32_bf16(v.x); o.y = f32_bf16(v.y);
    o.z = f32_bf16(v.z); o.w = f32_bf16(v.w);
    ((ushort4*)dst)[sub] = o;
}

// ---------------- Q|K GEMM: 256x256 4-phase counted-vmcnt ---------------
// (unchanged from round 5 — verified)
__global__ __launch_bounds__(512, 2) void gemm_qkv8(
    const unsigned short* __restrict__ A,
    const unsigned short* __restrict__ Wcat,
    const float* __restrict__ bq, const float* __restrict__ bk,
    const float* __restrict__ bv,
    unsigned short* __restrict__ qout, unsigned short* __restrict__ kout,
    unsigned short* __restrict__ vout) {
    extern __shared__ unsigned short lds[];

    const int tid  = threadIdx.x;
    const int wid  = tid >> 6;      // 0..7
    const int lane = tid & 63;
    const int quad = lane >> 4;     // 0..3
    const int lr   = lane & 15;
    const int wr   = wid >> 2;      // 0..1  (M)
    const int wc   = wid & 3;       // 0..3  (N)

    const int id   = blockIdx.y * 8 + blockIdx.x;
    const int xcd  = id & 7;
    const int rank = id >> 3;                 // 0..31
    const int by   = xcd * 4 + (rank >> 3);   // 0..31
    const int bx   = rank & 7;                // 0..7
    const int bm0  = by * 256;
    const int bn0  = bx * 256;                // 0..1792 (Q|K only)

    const int srow  = wid * 8 + (lane >> 3);            // 0..63
    const int scol  = ((lane & 7) ^ (lane >> 3)) * 8;   // swizzled src col
    const int sldso = wid * 512;                        // shorts

    const int a_r   = wr * 64 + lr;
    const int b_r   = wc * 32 + lr;
    const int slot0 = (quad ^ (lr & 7)) * 8;            // ks=0, shorts
    const int slot1 = ((quad ^ 4) ^ (lr & 7)) * 8;      // ks=1

    f32x4 acc[8][4];
    const f32x4 zero = {0.f, 0.f, 0.f, 0.f};
#pragma unroll
    for (int i = 0; i < 8; ++i)
#pragma unroll
        for (int j = 0; j < 4; ++j) acc[i][j] = zero;

    short8 areg[4][2];
    short8 breg[2][2][2];

#define STG(S, BUF, REG, GB, GROW)                                          \
    do {                                                                    \
        if ((S) < 16) {                                                     \
            unsigned short* lb = lds + ((BUF) * 4 + (REG)) * 8192 + sldso;  \
            const unsigned short* gp =                                      \
                (GB) + (size_t)((GROW) + srow) * Cc + (S) * 64 + scol;      \
            ASYNC16(gp, lb);                                                \
            ASYNC16(gp + (size_t)64 * Cc, lb + 4096);                       \
        }                                                                   \
    } while (0)

#define LDA(mh)                                                             \
    do {                                                                    \
        const unsigned short* ab = bufb + (mh) * 8192;                      \
        _Pragma("unroll") for (int mf = 0; mf < 4; ++mf) {                  \
            areg[mf][0] = *(const short8*)(ab + (a_r + mf * 16) * 64 + slot0); \
            areg[mf][1] = *(const short8*)(ab + (a_r + mf * 16) * 64 + slot1); \
        }                                                                   \
    } while (0)

#define LDB(nh)                                                             \
    do {                                                                    \
        const unsigned short* bb = bufb + (2 + (nh)) * 8192;                \
        _Pragma("unroll") for (int nf = 0; nf < 2; ++nf) {                  \
            breg[nh][nf][0] = *(const short8*)(bb + (b_r + nf * 16) * 64 + slot0); \
            breg[nh][nf][1] = *(const short8*)(bb + (b_r + nf * 16) * 64 + slot1); \
        }                                                                   \
    } while (0)

#define MFMA_PHASE(mh, nh)                                                  \
    _Pragma("unroll") for (int mf = 0; mf < 4; ++mf)                        \
    _Pragma("unroll") for (int nf = 0; nf < 2; ++nf) {                      \
        acc[(mh)*4+mf][(nh)*2+nf] = __builtin_amdgcn_mfma_f32_16x16x32_bf16( \
            areg[mf][0], breg[nh][nf][0], acc[(mh)*4+mf][(nh)*2+nf], 0,0,0); \
        acc[(mh)*4+mf][(nh)*2+nf] = __builtin_amdgcn_mfma_f32_16x16x32_bf16( \
            areg[mf][1], breg[nh][nf][1], acc[(mh)*4+mf][(nh)*2+nf], 0,0,0); \
    }

#define TILE(T, BC, WN)                                                     \
    {                                                                       \
        const unsigned short* bufb = lds + (BC) * 32768;                    \
        LDA(0);                                                             \
        LDB(0);                                                             \
        STG((T) + 1, (BC) ^ 1, 1, A, bm0 + 128);                            \
        __builtin_amdgcn_s_barrier();                                       \
        asm volatile("s_waitcnt lgkmcnt(0)" ::: "memory");                  \
        __builtin_amdgcn_s_setprio(1);                                      \
        MFMA_PHASE(0, 0);                                                   \
        __builtin_amdgcn_s_setprio(0);                                      \
        __builtin_amdgcn_s_barrier();                                       \
        LDB(1);                                                             \
        STG((T) + 1, (BC) ^ 1, 3, Wcat, bn0 + 128);                         \
        __builtin_amdgcn_s_barrier();                                       \
        asm volatile("s_waitcnt lgkmcnt(0)" ::: "memory");                  \
        __builtin_amdgcn_s_setprio(1);                                      \
        MFMA_PHASE(0, 1);                                                   \
        __builtin_amdgcn_s_setprio(0);                                      \
        __builtin_amdgcn_s_barrier();                                       \
        LDA(1);                                                             \
        STG((T) + 2, (BC), 0, A, bm0);                                      \
        __builtin_amdgcn_s_barrier();                                       \
        asm volatile("s_waitcnt lgkmcnt(0)" ::: "memory");                  \
        __builtin_amdgcn_s_setprio(1);                                      \
        MFMA_PHASE(1, 0);                                                   \
        __builtin_amdgcn_s_setprio(0);                                      \
        __builtin_amdgcn_s_barrier();                                       \
        STG((T) + 2, (BC), 2, Wcat, bn0);                                   \
        __builtin_amdgcn_s_barrier();                                       \
        __builtin_amdgcn_s_setprio(1);                                      \
        MFMA_PHASE(1, 1);                                                   \
        __builtin_amdgcn_s_setprio(0);                                      \
        asm volatile("s_waitcnt vmcnt(" #WN ")" ::: "memory");              \
        __builtin_amdgcn_s_barrier();                                       \
    }

    STG(0, 0, 0, A, bm0);
    STG(0, 0, 1, A, bm0 + 128);
    STG(0, 0, 2, Wcat, bn0);
    STG(0, 0, 3, Wcat, bn0 + 128);
    STG(1, 1, 0, A, bm0);
    STG(1, 1, 2, Wcat, bn0);
    asm volatile("s_waitcnt vmcnt(4)" ::: "memory");
    __builtin_amdgcn_s_barrier();

    for (int t2 = 0; t2 < 7; ++t2) {
        const int T0 = t2 * 2;
        TILE(T0, 0, 4);
        TILE(T0 + 1, 1, 4);
    }
    TILE(14, 0, 0);
    TILE(15, 1, 0);

#undef TILE
#undef MFMA_PHASE
#undef LDB
#undef LDA
#undef STG

    const int which = bn0 >> 10;  // 0=q 1=k (v handled by gemm_v8)
    const float* bias = (which == 0) ? bq : bk;
    unsigned short* outp = (which == 0) ? qout : kout;
    const float scale = (which == 0) ? 0.1803368801111204f : 1.0f;  // 0.125*log2e
    const int nb = bn0 & 1023;
    (void)bv; (void)vout;

#pragma unroll
    for (int nh = 0; nh < 2; ++nh)
#pragma unroll
        for (int nf = 0; nf < 2; ++nf) {
            const int nl = nb + nh * 128 + wc * 32 + nf * 16 + lr;
            const float bvv = bias[nl];
            const int h = nl >> 6, hd = nl & 63;
#pragma unroll
            for (int mh = 0; mh < 2; ++mh)
#pragma unroll
                for (int mf = 0; mf < 4; ++mf) {
                    const f32x4 a = acc[mh * 4 + mf][nh * 2 + nf];
                    const int m0 = bm0 + mh * 128 + wr * 64 + mf * 16 + quad * 4;
                    const int b = m0 >> 11, t0 = m0 & 2047;
#pragma unroll
                    for (int r = 0; r < 4; ++r) {
                        outp[(((size_t)(b * Hh + h)) * Tt + t0 + r) * HDd + hd] =
                            f32_bf16_rn((a[r] + bvv) * scale);
                    }
                }
        }
}

// ---------------- V GEMM: 256x128 2-phase (gemm_proj8 clone) -------------
// (unchanged from round 5 — verified)
__global__ __launch_bounds__(512, 2) void gemm_v8(
    const unsigned short* __restrict__ A,
    const unsigned short* __restrict__ Wcat,
    const float* __restrict__ bv,
    unsigned short* __restrict__ vout) {
    extern __shared__ unsigned short lds[];

    const int tid  = threadIdx.x;
    const int wid  = tid >> 6;
    const int lane = tid & 63;
    const int quad = lane >> 4;
    const int lr   = lane & 15;
    const int wr   = wid >> 2;      // 0..1
    const int wc   = wid & 3;       // 0..3

    const int id   = blockIdx.y * 8 + blockIdx.x;
    const int xcd  = id & 7;
    const int rank = id >> 3;
    const int by   = xcd * 4 + (rank >> 3);  // 0..31
    const int bx   = rank & 7;               // 0..7
    const int bm0  = by * 256;
    const int wrow0 = 2048 + bx * 128;       // row in Wcat

    const int srow  = wid * 8 + (lane >> 3);
    const int scol  = ((lane & 7) ^ (lane >> 3)) * 8;
    const int sldso = wid * 512;

    const int a_r   = wr * 64 + lr;
    const int b_r2  = (wc & 1) * 32 + lr;
    const int breg_off = 16384 + (wc >> 1) * 4096;
    const int slot0 = (quad ^ (lr & 7)) * 8;
    const int slot1 = ((quad ^ 4) ^ (lr & 7)) * 8;

    f32x4 acc[8][2];
    const f32x4 zero = {0.f, 0.f, 0.f, 0.f};
#pragma unroll
    for (int i = 0; i < 8; ++i)
#pragma unroll
        for (int j = 0; j < 2; ++j) acc[i][j] = zero;

    short8 areg[4][2];
    short8 breg[2][2];

#define STGAV(S, BUF, REG_OFF, GROW)                                        \
    do {                                                                    \
        if ((S) < 16) {                                                     \
            unsigned short* lb = lds + (BUF) * 24576 + (REG_OFF) + sldso;   \
            const unsigned short* gp =                                      \
                A + (size_t)(bm0 + (GROW) + srow) * Cc + (S) * 64 + scol;   \
            ASYNC16(gp, lb);                                                \
            ASYNC16(gp + (size_t)64 * Cc, lb + 4096);                       \
        }                                                                   \
    } while (0)

#define STGBV(S, BUF, REG_OFF, NROW)                                        \
    do {                                                                    \
        if ((S) < 16) {                                                     \
            unsigned short* lb = lds + (BUF) * 24576 + (REG_OFF) + sldso;   \
            const unsigned short* gp =                                      \
                Wcat + (size_t)(wrow0 + (NROW) + srow) * Cc + (S) * 64 + scol; \
            ASYNC16(gp, lb);                                                \
        }                                                                   \
    } while (0)

#define LDA_V(mh)                                                           \
    do {                                                                    \
        const unsigned short* ab = bufb + (mh) * 8192;                      \
        _Pragma("unroll") for (int mf = 0; mf < 4; ++mf) {                  \
            areg[mf][0] = *(const short8*)(ab + (a_r + mf * 16) * 64 + slot0); \
            areg[mf][1] = *(const short8*)(ab + (a_r + mf * 16) * 64 + slot1); \
        }                                                                   \
    } while (0)

#define LDB_V                                                               \
    do {                                                                    \
        const unsigned short* bb = bufb + breg_off;                         \
        _Pragma("unroll") for (int nf = 0; nf < 2; ++nf) {                  \
            breg[nf][0] = *(const short8*)(bb + (b_r2 + nf * 16) * 64 + slot0); \
            breg[nf][1] = *(const short8*)(bb + (b_r2 + nf * 16) * 64 + slot1); \
        }                                                                   \
    } while (0)

#define MFMA_V(mh)                                                          \
    _Pragma("unroll") for (int mf = 0; mf < 4; ++mf)                        \
    _Pragma("unroll") for (int nf = 0; nf < 2; ++nf) {                      \
        acc[(mh)*4+mf][nf] = __builtin_amdgcn_mfma_f32_16x16x32_bf16(       \
            areg[mf][0], breg[nf][0], acc[(mh)*4+mf][nf], 0, 0, 0);         \
        acc[(mh)*4+mf][nf] = __builtin_amdgcn_mfma_f32_16x16x32_bf16(       \
            areg[mf][1], breg[nf][1], acc[(mh)*4+mf][nf], 0, 0, 0);         \
    }

#define TILE_V(T, BC, WN)                                                   \
    {                                                                       \
        const unsigned short* bufb = lds + (BC) * 24576;                    \
        LDA_V(0);                                                           \
        LDB_V;                                                              \
        STGAV((T) + 1, (BC) ^ 1, 8192, 128);                                \
        STGBV((T) + 1, (BC) ^ 1, 20480, 64);                                \
        __builtin_amdgcn_s_barrier();                                       \
        asm volatile("s_waitcnt lgkmcnt(0)" ::: "memory");                  \
        __builtin_amdgcn_s_setprio(1);                                      \
        MFMA_V(0);                                                          \
        __builtin_amdgcn_s_setprio(0);                                      \
        __builtin_amdgcn_s_barrier();                                       \
        LDA_V(1);                                                           \
        STGAV((T) + 2, (BC), 0, 0);                                         \
        STGBV((T) + 2, (BC), 16384, 0);                                     \
        __builtin_amdgcn_s_barrier();                                       \
        asm volatile("s_waitcnt lgkmcnt(0)" ::: "memory");                  \
        __builtin_amdgcn_s_setprio(1);                                      \
        MFMA_V(1);                                                          \
        __builtin_amdgcn_s_setprio(0);                                      \
        asm volatile("s_waitcnt vmcnt(" #WN ")" ::: "memory");              \
        __builtin_amdgcn_s_barrier();                                       \
    }

    STGAV(0, 0, 0, 0);
    STGAV(0, 0, 8192, 128);
    STGBV(0, 0, 16384, 0);
    STGBV(0, 0, 20480, 64);
    STGAV(1, 1, 0, 0);
    STGBV(1, 1, 16384, 0);
    asm volatile("s_waitcnt vmcnt(3)" ::: "memory");
    __builtin_amdgcn_s_barrier();

    for (int t2 = 0; t2 < 7; ++t2) {
        const int T0 = t2 * 2;
        TILE_V(T0, 0, 3);
        TILE_V(T0 + 1, 1, 3);
    }
    TILE_V(14, 0, 0);
    TILE_V(15, 1, 0);

#undef TILE_V
#undef MFMA_V
#undef LDB_V
#undef LDA_V
#undef STGBV
#undef STGAV

    // v epilogue: bf16 [B,H,HD,T], ushort4 along T
#pragma unroll
    for (int nf = 0; nf < 2; ++nf) {
        const int nl = (wrow0 - 2048) + wc * 32 + nf * 16 + lr;  // 0..1023
        const float bvv = bv[nl];
        const int h = nl >> 6, hd = nl & 63;
#pragma unroll
        for (int mh = 0; mh < 2; ++mh)
#pragma unroll
            for (int mf = 0; mf < 4; ++mf) {
                const f32x4 a = acc[mh * 4 + mf][nf];
                const int m0 = bm0 + mh * 128 + wr * 64 + mf * 16 + quad * 4;
                const int b = m0 >> 11, t0 = m0 & 2047;
                ushort4 pk;
                pk.x = f32_bf16_rn(a[0] + bvv);
                pk.y = f32_bf16_rn(a[1] + bvv);
                pk.z = f32_bf16_rn(a[2] + bvv);
                pk.w = f32_bf16_rn(a[3] + bvv);
                *(ushort4*)(vout + (((size_t)(b * Hh + h)) * HDd + hd) * Tt + t0) = pk;
            }
    }
}

// ---------------- output projection GEMM: 256x128 2-phase template -------
// (unchanged from round 3 — verified)
__global__ __launch_bounds__(512, 2) void gemm_proj8(
    const unsigned short* __restrict__ A,
    const unsigned short* __restrict__ W,
    const float* __restrict__ bias,
    float* __restrict__ out) {
    extern __shared__ unsigned short lds[];

    const int tid  = threadIdx.x;
    const int wid  = tid >> 6;
    const int lane = tid & 63;
    const int quad = lane >> 4;
    const int lr   = lane & 15;
    const int wr   = wid >> 2;      // 0..1
    const int wc   = wid & 3;       // 0..3

    const int id   = blockIdx.y * 8 + blockIdx.x;
    const int xcd  = id & 7;
    const int rank = id >> 3;          // 0..31
    const int by   = xcd * 4 + (rank >> 3);  // 0..31
    const int bx   = rank & 7;               // 0..7
    const int bm0  = by * 256;
    const int bn0  = bx * 128;

    const int srow  = wid * 8 + (lane >> 3);
    const int scol  = ((lane & 7) ^ (lane >> 3)) * 8;
    const int sldso = wid * 512;

    const int a_r   = wr * 64 + lr;
    const int b_r2  = (wc & 1) * 32 + lr;     // row within own B region
    const int breg_off = 16384 + (wc >> 1) * 4096;  // wave's B region
    const int slot0 = (quad ^ (lr & 7)) * 8;
    const int slot1 = ((quad ^ 4) ^ (lr & 7)) * 8;

    f32x4 acc[8][2];
    const f32x4 zero = {0.f, 0.f, 0.f, 0.f};
#pragma unroll
    for (int i = 0; i < 8; ++i)
#pragma unroll
        for (int j = 0; j < 2; ++j) acc[i][j] = zero;

    short8 areg[4][2];
    short8 breg[2][2];

#define STGA(S, BUF, REG_OFF, GROW)                                         \
    do {                                                                    \
        if ((S) < 16) {                                                     \
            unsigned short* lb = lds + (BUF) * 24576 + (REG_OFF) + sldso;   \
            const unsigned short* gp =                                      \
                A + (size_t)(bm0 + (GROW) + srow) * Cc + (S) * 64 + scol;   \
            ASYNC16(gp, lb);                                                \
            ASYNC16(gp + (size_t)64 * Cc, lb + 4096);                       \
        }                                                                   \
    } while (0)

#define STGB(S, BUF, REG_OFF, NROW)                                         \
    do {                                                                    \
        if ((S) < 16) {                                                     \
            unsigned short* lb = lds + (BUF) * 24576 + (REG_OFF) + sldso;   \
            const unsigned short* gp =                                      \
                W + (size_t)(bn0 + (NROW) + srow) * Cc + (S) * 64 + scol;   \
            ASYNC16(gp, lb);                                                \
        }                                                                   \
    } while (0)

#define LDA_P(mh)                                                           \
    do {                                                                    \
        const unsigned short* ab = bufb + (mh) * 8192;                      \
        _Pragma("unroll") for (int mf = 0; mf < 4; ++mf) {                  \
            areg[mf][0] = *(const short8*)(ab + (a_r + mf * 16) * 64 + slot0); \
            areg[mf][1] = *(const short8*)(ab + (a_r + mf * 16) * 64 + slot1); \
        }                                                                   \
    } while (0)

#define LDB_P                                                               \
    do {                                                                    \
        const unsigned short* bb = bufb + breg_off;                         \
        _Pragma("unroll") for (int nf = 0; nf < 2; ++nf) {                  \
            breg[nf][0] = *(const short8*)(bb + (b_r2 + nf * 16) * 64 + slot0); \
            breg[nf][1] = *(const short8*)(bb + (b_r2 + nf * 16) * 64 + slot1); \
        }                                                                   \
    } while (0)

#define MFMA_P(mh)                                                          \
    _Pragma("unroll") for (int mf = 0; mf < 4; ++mf)                        \
    _Pragma("unroll") for (int nf = 0; nf < 2; ++nf) {                      \
        acc[(mh)*4+mf][nf] = __builtin_amdgcn_mfma_f32_16x16x32_bf16(       \
            areg[mf][0], breg[nf][0], acc[(mh)*4+mf][nf], 0, 0, 0);         \
        acc[(mh)*4+mf][nf] = __builtin_amdgcn_mfma_f32_16x16x32_bf16(       \
            areg[mf][1], breg[nf][1], acc[(mh)*4+mf][nf], 0, 0, 0);         \
    }

#define TILE_P(T, BC, WN)                                                   \
    {                                                                       \
        const unsigned short* bufb = lds + (BC) * 24576;                    \
        LDA_P(0);                                                           \
        LDB_P;                                                              \
        STGA((T) + 1, (BC) ^ 1, 8192, 128);                                 \
        STGB((T) + 1, (BC) ^ 1, 20480, 64);                                 \
        __builtin_amdgcn_s_barrier();                                       \
        asm volatile("s_waitcnt lgkmcnt(0)" ::: "memory");                  \
        __builtin_amdgcn_s_setprio(1);                                      \
        MFMA_P(0);                                                          \
        __builtin_amdgcn_s_setprio(0);                                      \
        __builtin_amdgcn_s_barrier();                                       \
        LDA_P(1);                                                           \
        STGA((T) + 2, (BC), 0, 0);                                          \
        STGB((T) + 2, (BC), 16384, 0);                                      \
        __builtin_amdgcn_s_barrier();                                       \
        asm volatile("s_waitcnt lgkmcnt(0)" ::: "memory");                  \
        __builtin_amdgcn_s_setprio(1);                                      \
        MFMA_P(1);                                                          \
        __builtin_amdgcn_s_setprio(0);                                      \
        asm volatile("s_waitcnt vmcnt(" #WN ")" ::: "memory");              \
        __builtin_amdgcn_s_barrier();                                       \
    }

    STGA(0, 0, 0, 0);
    STGA(0, 0, 8192, 128);
    STGB(0, 0, 16384, 0);
    STGB(0, 0, 20480, 64);
    STGA(1, 1, 0, 0);
    STGB(1, 1, 16384, 0);
    asm volatile("s_waitcnt vmcnt(3)" ::: "memory");
    __builtin_amdgcn_s_barrier();

    for (int t2 = 0; t2 < 7; ++t2) {
        const int T0 = t2 * 2;
        TILE_P(T0, 0, 3);
        TILE_P(T0 + 1, 1, 3);
    }
    TILE_P(14, 0, 0);
    TILE_P(15, 1, 0);

#undef TILE_P
#undef MFMA_P
#undef LDB_P
#undef LDA_P
#undef STGB
#undef STGA

#pragma unroll
    for (int nf = 0; nf < 2; ++nf) {
        const int n = bn0 + wc * 32 + nf * 16 + lr;
        const float bvv = bias[n];
#pragma unroll
        for (int mh = 0; mh < 2; ++mh)
#pragma unroll
            for (int mf = 0; mf < 4; ++mf) {
                const f32x4 a = acc[mh * 4 + mf][nf];
                const int m0 = bm0 + mh * 128 + wr * 64 + mf * 16 + quad * 4;
#pragma unroll
                for (int r = 0; r < 4; ++r)
                    out[(size_t)(m0 + r) * Cc + n] = a[r] + bvv;
            }
    }
}

// ---------------- flash attention: 32x32 MFMA, in-register softmax -------
// Round-6 rewrite. grid (64, 8): head = blockIdx.x, qx = blockIdx.y;
// passes qt = qx and 15-qx over 16 q-tiles of 128 rows -> 34 k-tile iters
// per block; 512 blocks x 32768 B LDS = 2 blocks/CU (one generation).
// Block = 4 waves x 32 q-rows. Swapped QK^T (mfma32(K,Q)) gives S^T:
// lane l holds S[q=l&31][k=(r&3)+8(r>>2)+4(l>>5)] per 32-k tile -> row
// softmax is in-lane (+1 shfl_xor(32) at the end). P->A-frag for PV via
// 16 v_cvt_pk_bf16_f32 + 8 v_permlane32_swap_b32 per 64-k tile (T12) —
// NO P LDS round-trip (old: 16 ds_write + 2 ds_read + lgkm chain/iter).
// K/V staging + XOR swizzle identical to the verified round-2 code.
// Per-wave early-out skips fully-above-diagonal tiles (barrier still hit).
__global__ __launch_bounds__(256, 2) void attn(const unsigned short* __restrict__ q,
                                               const unsigned short* __restrict__ k,
                                               const unsigned short* __restrict__ vt,
                                               unsigned short* __restrict__ y) {
    __shared__ unsigned short sK[2][64 * 64];
    __shared__ unsigned short sV[2][64 * 64];

    const int tid  = threadIdx.x;
    const int wid  = tid >> 6;
    const int lane = tid & 63;
    const int l31  = lane & 31;
    const int hb   = lane >> 5;       // half-wave
    const int x7   = lane & 7;

    const int bh = blockIdx.x;        // head
    const int qx = blockIdx.y;        // 0..7
    const size_t headq = (size_t)bh * Tt * HDd;
    const unsigned short* kg = k + headq;
    const unsigned short* vg = vt + headq;
    const int b = bh >> 4, h = bh & 15;

    // staging (verified): each wave stages 16 K rows + 16 V rows per tile
    const int g_r = lane >> 3;                       // 0..7
    const int g_c = ((lane & 7) ^ g_r) * 8;          // pre-swizzled src col
    const unsigned short* kst = kg + (size_t)(wid * 16 + g_r) * HDd + g_c;
    const unsigned short* vst = vg + (size_t)(wid * 16 + g_r) * Tt + g_c;
    unsigned short* dK0 = sK[0] + wid * 1024;
    unsigned short* dK1 = sK[1] + wid * 1024;
    unsigned short* dV0 = sV[0] + wid * 1024;
    unsigned short* dV1 = sV[1] + wid * 1024;

#define STAGE_KV(BUF, KB)                                                   \
    do {                                                                    \
        unsigned short* dK = (BUF) ? dK1 : dK0;                             \
        unsigned short* dV = (BUF) ? dV1 : dV0;                             \
        ASYNC16(kst + (size_t)(KB) * HDd,       dK);                        \
        ASYNC16(kst + (size_t)((KB) + 8) * HDd, dK + 512);                  \
        ASYNC16(vst + (KB),                     dV);                        \
        ASYNC16(vst + (size_t)8 * Tt + (KB),    dV + 512);                  \
    } while (0)

#define CVTPK(d, a, bb) asm("v_cvt_pk_bf16_f32 %0, %1, %2" : "=v"(d) : "v"(a), "v"(bb))
#define PLSWAP(xx, yy)  asm("v_permlane32_swap_b32 %0, %1" : "+v"(xx), "+v"(yy))

    // swizzled fragment read: element (row, col8): off = row*64 + ((col8^ (row&7))*8)
    // all tile row-bases are multiples of 32 -> row&7 == x7.
    const int frow = l31 * 64;

    const f32x16 zero16 = {0.f,0.f,0.f,0.f,0.f,0.f,0.f,0.f,
                           0.f,0.f,0.f,0.f,0.f,0.f,0.f,0.f};

    // per-wave tile count: nw = 2qt + 1 + (wid>>1); ntiles = 2qt+2
    const int nwoff = 1 + (wid >> 1);

    for (int pass = 0; pass < 2; ++pass) {
        const int qt = pass ? (15 - qx) : qx;
        const int qb = qt * 128;
        const int ntiles = 2 * qt + 2;
        const int nw = 2 * qt + nwoff;

        const unsigned short* qp =
            q + headq + (size_t)(qb + wid * 32 + l31) * HDd;
        short8 qf[4];
#pragma unroll
        for (int c = 0; c < 4; c++)
            qf[c] = *(const short8*)(qp + c * 16 + hb * 8);

        f32x16 o0 = zero16, o1 = zero16;
        float l_run = 0.f;

        STAGE_KV(0, 0);
        __syncthreads();

        for (int kt = 0; kt < ntiles; ++kt) {
            const int cur = kt & 1;
            if (kt + 1 < ntiles) STAGE_KV(cur ^ 1, (kt + 1) * 64);

            if (kt < nw) {
                const unsigned short* bK = sK[cur];
                const unsigned short* bV = sV[cur];

                // QK^T swapped: p0 (k 0..31), p1 (k 32..63)
                f32x16 p0 = zero16, p1 = zero16;
                __builtin_amdgcn_s_setprio(1);
#pragma unroll
                for (int c = 0; c < 4; c++) {
                    const int cs = ((2 * c + hb) ^ x7) * 8;
                    short8 kf0 = *(const short8*)(bK + frow + cs);
                    short8 kf1 = *(const short8*)(bK + 2048 + frow + cs);
                    p0 = __builtin_amdgcn_mfma_f32_32x32x16_bf16(kf0, qf[c], p0, 0, 0, 0);
                    p1 = __builtin_amdgcn_mfma_f32_32x32x16_bf16(kf1, qf[c], p1, 0, 0, 0);
                }
                __builtin_amdgcn_s_setprio(0);

                // causal mask (only the diagonal tile)
                if (kt == nw - 1 || kt == ntiles - 1) {
                    const int qd = qb + wid * 32 + l31 - kt * 64 - 4 * hb;
#pragma unroll
                    for (int r = 0; r < 16; r++) {
                        const int kb0 = (r & 3) + 8 * (r >> 2);
                        p0[r] = (kb0 <= qd) ? p0[r] : -INFINITY;
                        p1[r] = (kb0 + 32 <= qd) ? p1[r] : -INFINITY;
                    }
                }

                // exp2 + row-sum (in-lane) + pack pairs
                float lacc = 0.f;
#pragma unroll
                for (int r = 0; r < 16; r++) {
                    p0[r] = fast_exp2(p0[r]); lacc += p0[r];
                    p1[r] = fast_exp2(p1[r]); lacc += p1[r];
                }
                l_run += lacc;

                unsigned w0[4][2], w1[4][2];
#pragma unroll
                for (int g = 0; g < 4; g++) {
                    CVTPK(w0[g][0], p0[4 * g + 0], p0[4 * g + 1]);
                    CVTPK(w0[g][1], p0[4 * g + 2], p0[4 * g + 3]);
                    CVTPK(w1[g][0], p1[4 * g + 0], p1[4 * g + 1]);
                    CVTPK(w1[g][1], p1[4 * g + 2], p1[4 * g + 3]);
                }

                // PV: per k-16 chunk kc: A-frag via permlane32_swap, B = V
                __builtin_amdgcn_s_setprio(1);
#pragma unroll
                for (int kc = 0; kc < 4; kc++) {
                    unsigned x0, x1, y0, y1;
                    if (kc == 0)      { x0 = w0[0][0]; x1 = w0[0][1]; y0 = w0[1][0]; y1 = w0[1][1]; }
                    else if (kc == 1) { x0 = w0[2][0]; x1 = w0[2][1]; y0 = w0[3][0]; y1 = w0[3][1]; }
                    else if (kc == 2) { x0 = w1[0][0]; x1 = w1[0][1]; y0 = w1[1][0]; y1 = w1[1][1]; }
                    else              { x0 = w1[2][0]; x1 = w1[2][1]; y0 = w1[3][0]; y1 = w1[3][1]; }
                    PLSWAP(x0, y0);
                    PLSWAP(x1, y1);
                    union { unsigned u[4]; short8 s; } pu;
                    pu.u[0] = x0; pu.u[1] = x1; pu.u[2] = y0; pu.u[3] = y1;

                    const int vs = ((2 * kc + hb) ^ x7) * 8;
                    short8 vf0 = *(const short8*)(bV + frow + vs);
                    short8 vf1 = *(const short8*)(bV + 2048 + frow + vs);
                    o0 = __builtin_amdgcn_mfma_f32_32x32x16_bf16(pu.s, vf0, o0, 0, 0, 0);
                    o1 = __builtin_amdgcn_mfma_f32_32x32x16_bf16(pu.s, vf1, o1, 0, 0, 0);
                }
                __builtin_amdgcn_s_setprio(0);
            }

            __syncthreads();
        }

        // normalize + write
        l_run += __shfl_xor(l_run, 32);
        const float inv = 1.0f / l_run;
        unsigned short* yp = y + (size_t)(b * Tt + qb + wid * 32) * Cc + h * HDd;
#pragma unroll
        for (int r = 0; r < 16; r++) {
            const int qr = (r & 3) + 8 * (r >> 2) + 4 * hb;
            const float invr = __shfl(inv, qr);
            yp[(size_t)qr * Cc + l31]      = f32_bf16_rn(o0[r] * invr);
            yp[(size_t)qr * Cc + 32 + l31] = f32_bf16_rn(o1[r] * invr);
        }
    }
#undef STAGE_KV
#undef CVTPK
#undef PLSWAP
}

// ---------------- launch ----------------
extern "C" void kernel_launch(void* const* d_in, const int* in_sizes, int n_in,
                              void* d_out, int out_size, void* d_ws, size_t ws_size,
                              hipStream_t stream) {
    const float* x  = (const float*)d_in[0];
    const float* Wk = (const float*)d_in[1];
    const float* bk = (const float*)d_in[2];
    const float* Wq = (const float*)d_in[3];
    const float* bq = (const float*)d_in[4];
    const float* Wv = (const float*)d_in[5];
    const float* bv = (const float*)d_in[6];
    const float* Wp = (const float*)d_in[7];
    const float* bp = (const float*)d_in[8];
    float* out = (float*)d_out;

    char* ws = (char*)d_ws;
    size_t off = 0;
    auto alloc = [&](size_t bytes) { char* p = ws + off; off += bytes; return p; };
    const size_t MK = (size_t)8192 * 1024;
    const size_t NK = (size_t)1024 * 1024;
    unsigned short* xb   = (unsigned short*)alloc(MK * 2);
    unsigned short* Wcat = (unsigned short*)alloc(3 * NK * 2);  // q|k|v contiguous
    unsigned short* Wqb  = Wcat;
    unsigned short* Wkb  = Wcat + NK;
    unsigned short* Wvb  = Wcat + 2 * NK;
    unsigned short* Wpb  = (unsigned short*)alloc(NK * 2);
    unsigned short* qh   = (unsigned short*)alloc(MK * 2);  // [B,H,T,HD], pre-scaled
    unsigned short* kh   = (unsigned short*)alloc(MK * 2);  // [B,H,T,HD]
    unsigned short* vth  = (unsigned short*)alloc(MK * 2);  // [B,H,HD,T]
    unsigned short* ya   = (unsigned short*)alloc(MK * 2);  // [B,T,C]

    static bool lds_attr_set = false;
    if (!lds_attr_set) {
        (void)hipFuncSetAttribute((const void*)gemm_qkv8,
                                  hipFuncAttributeMaxDynamicSharedMemorySize,
                                  131072);
        (void)hipFuncSetAttribute((const void*)gemm_v8,
                                  hipFuncAttributeMaxDynamicSharedMemorySize,
                                  98304);
        (void)hipFuncSetAttribute((const void*)gemm_proj8,
                                  hipFuncAttributeMaxDynamicSharedMemorySize,
                                  98304);
        lds_attr_set = true;
    }

    cvt_all<<<12288, 256, 0, stream>>>(x, Wq, Wk, Wv, Wp, xb, Wqb, Wkb, Wvb, Wpb);

    gemm_qkv8<<<dim3(8, 32), 512, 131072, stream>>>(xb, Wcat, bq, bk, bv, qh, kh, vth);
    gemm_v8<<<dim3(8, 32), 512, 98304, stream>>>(xb, Wcat, bv, vth);

    attn<<<dim3(64, 8), 256, 0, stream>>>(qh, kh, vth, ya);

    gemm_proj8<<<dim3(8, 32), 512, 98304, stream>>>(ya, Wpb, bp, out);
}